// Round 3
// baseline (190.481 us; speedup 1.0000x reference)
//
#include <hip/hip_runtime.h>

#define N_ITEMS 65536

// ---------------- Kernel 1: qpart[z] = x @ W (K-chunk 256 per z) ----------------
__launch_bounds__(256)
__global__ void gemm_q_kernel(const float* __restrict__ A,
                              const float* __restrict__ W,
                              float* __restrict__ qpart) {
  __shared__ float As[16][132];
  __shared__ float Bs[16][132];
  const int tid = threadIdx.x;
  const int tx = tid & 15, ty = tid >> 4;
  const int rb = blockIdx.y * 128, cb = blockIdx.x * 128;
  const int kz = blockIdx.z * 256;
  const int ar = tid >> 2, ac = (tid & 3) << 2;
  const int bk = tid >> 5, bc = (tid & 31) << 2;

  float4 va0 = *(const float4*)&A[(rb + ar) * 1024 + kz + ac];
  float4 va1 = *(const float4*)&A[(rb + ar + 64) * 1024 + kz + ac];
  float4 vb0 = *(const float4*)&W[(kz + bk) * 1024 + cb + bc];
  float4 vb1 = *(const float4*)&W[(kz + bk + 8) * 1024 + cb + bc];

  float acc[8][8] = {};
  for (int k0 = 0; k0 < 256; k0 += 16) {
    As[ac + 0][ar] = va0.x; As[ac + 1][ar] = va0.y;
    As[ac + 2][ar] = va0.z; As[ac + 3][ar] = va0.w;
    As[ac + 0][ar + 64] = va1.x; As[ac + 1][ar + 64] = va1.y;
    As[ac + 2][ar + 64] = va1.z; As[ac + 3][ar + 64] = va1.w;
    *(float4*)&Bs[bk][bc] = vb0;
    *(float4*)&Bs[bk + 8][bc] = vb1;
    __syncthreads();
    if (k0 + 16 < 256) {
      va0 = *(const float4*)&A[(rb + ar) * 1024 + kz + k0 + 16 + ac];
      va1 = *(const float4*)&A[(rb + ar + 64) * 1024 + kz + k0 + 16 + ac];
      vb0 = *(const float4*)&W[(kz + k0 + 16 + bk) * 1024 + cb + bc];
      vb1 = *(const float4*)&W[(kz + k0 + 16 + bk + 8) * 1024 + cb + bc];
    }
#pragma unroll
    for (int kk = 0; kk < 16; kk++) {
      const float4 a0 = *(const float4*)&As[kk][ty << 2];
      const float4 a1 = *(const float4*)&As[kk][64 + (ty << 2)];
      const float4 b0 = *(const float4*)&Bs[kk][tx << 2];
      const float4 b1 = *(const float4*)&Bs[kk][64 + (tx << 2)];
      const float ar8[8] = {a0.x, a0.y, a0.z, a0.w, a1.x, a1.y, a1.z, a1.w};
      const float br8[8] = {b0.x, b0.y, b0.z, b0.w, b1.x, b1.y, b1.z, b1.w};
#pragma unroll
      for (int r = 0; r < 8; r++)
#pragma unroll
        for (int c = 0; c < 8; c++)
          acc[r][c] = fmaf(ar8[r], br8[c], acc[r][c]);
    }
    __syncthreads();
  }
  float* outp = qpart + blockIdx.z * 1048576;
#pragma unroll
  for (int rh = 0; rh < 2; rh++)
#pragma unroll
    for (int r = 0; r < 4; r++) {
      const int row = rb + rh * 64 + (ty << 2) + r;
      const int ri = rh * 4 + r;
      *(float4*)&outp[row * 1024 + cb + (tx << 2)] =
          make_float4(acc[ri][0], acc[ri][1], acc[ri][2], acc[ri][3]);
      *(float4*)&outp[row * 1024 + cb + 64 + (tx << 2)] =
          make_float4(acc[ri][4], acc[ri][5], acc[ri][6], acc[ri][7]);
    }
}

// ---------------- Kernel 2: lut + in-register qsq/csq + code packing ----------
// pack plane (4-row b64 table): h = segment-local byte offset:
//   h = (c>>1)*128 + (c&1)*8   (max 16264, fits u16).
// Replica base (16r) and segment base (s*16384) are added in the scan kernel.
__launch_bounds__(256)
__global__ void lut_kernel(const float* __restrict__ qpart,
                           const float* __restrict__ kcb,
                           const int* __restrict__ key_codes,
                           float* __restrict__ lut,
                           unsigned long long* __restrict__ pcodes,
                           uint4* __restrict__ poffs) {
  if (blockIdx.z == 8) {
    const int g0 = (((int)blockIdx.y * 4 + (int)blockIdx.x) * 256 + (int)threadIdx.x) * 4;
#pragma unroll
    for (int t = 0; t < 4; t++) {
      const int gid = g0 + t;
      unsigned long long p = 0ull;
      unsigned h[8];
#pragma unroll
      for (int j = 0; j < 8; j++) {
        const unsigned c = (unsigned)key_codes[gid * 8 + j] & 255u;
        p |= (unsigned long long)c << (8 * j);
        h[j] = ((c >> 1) << 7) | ((c & 1u) << 3);
      }
      pcodes[gid] = p;
      poffs[gid] = make_uint4(h[0] | (h[1] << 16), h[2] | (h[3] << 16),
                              h[4] | (h[5] << 16), h[6] | (h[7] << 16));
    }
    return;
  }

  __shared__ float As[32][68];
  __shared__ float Bs[32][68];
  const int tid = threadIdx.x;
  const int tx = tid & 15, ty = tid >> 4;
  const int m = blockIdx.z;
  const int rb = blockIdx.y * 64;
  const int cb0 = blockIdx.x * 64;
  float acc[4][4] = {};
  float qa[4] = {}, cs[4] = {};
  for (int k0 = 0; k0 < 128; k0 += 32) {
#pragma unroll
    for (int l = 0; l < 2; l++) {
      const int e = tid + l * 256;
      const int row = e >> 3, c4 = (e & 7) << 2;
      const int qidx = (rb + row) * 1024 + m * 128 + k0 + c4;
      const float4 p0 = *(const float4*)&qpart[qidx];
      const float4 p1 = *(const float4*)&qpart[qidx + 1048576];
      const float4 p2 = *(const float4*)&qpart[qidx + 2097152];
      const float4 p3 = *(const float4*)&qpart[qidx + 3145728];
      const float4 va = make_float4(p0.x + p1.x + p2.x + p3.x,
                                    p0.y + p1.y + p2.y + p3.y,
                                    p0.z + p1.z + p2.z + p3.z,
                                    p0.w + p1.w + p2.w + p3.w);
      As[c4 + 0][row] = va.x; As[c4 + 1][row] = va.y;
      As[c4 + 2][row] = va.z; As[c4 + 3][row] = va.w;
      const float4 vb = *(const float4*)&kcb[(m * 256 + cb0 + row) * 128 + k0 + c4];
      Bs[c4 + 0][row] = vb.x; Bs[c4 + 1][row] = vb.y;
      Bs[c4 + 2][row] = vb.z; Bs[c4 + 3][row] = vb.w;
    }
    __syncthreads();
#pragma unroll
    for (int kk = 0; kk < 32; kk++) {
      const float4 a = *(const float4*)&As[kk][ty << 2];
      const float4 b = *(const float4*)&Bs[kk][tx << 2];
      const float ar[4] = {a.x, a.y, a.z, a.w};
      const float br[4] = {b.x, b.y, b.z, b.w};
#pragma unroll
      for (int r = 0; r < 4; r++)
#pragma unroll
        for (int c = 0; c < 4; c++)
          acc[r][c] = fmaf(ar[r], br[c], acc[r][c]);
#pragma unroll
      for (int r = 0; r < 4; r++) qa[r] = fmaf(ar[r], ar[r], qa[r]);
#pragma unroll
      for (int c = 0; c < 4; c++) cs[c] = fmaf(br[c], br[c], cs[c]);
    }
    __syncthreads();
  }
#pragma unroll
  for (int r = 0; r < 4; r++) {
    const int row = rb + (ty << 2) + r;
    const int col = cb0 + (tx << 2);
    float4 v;
    v.x = qa[r] + cs[0] - 2.0f * acc[r][0];
    v.y = qa[r] + cs[1] - 2.0f * acc[r][1];
    v.z = qa[r] + cs[2] - 2.0f * acc[r][2];
    v.w = qa[r] + cs[3] - 2.0f * acc[r][3];
    *(float4*)&lut[row * 2048 + m * 256 + col] = v;
  }
}

// ---------------- Kernel 3a: 4-ROW ADC scan, 32-deep pipelined b64 lookups --
// R2 post-mortem: 2-deep ping-pong (8 reads in flight) got 56->51us but
// VGPR=32 shows the queue never went deep; LDS (~75k cyc) and VALU (~71k)
// are balanced at ~60% each -> ~40k cyc of dependency bubbles remain.
// Fix: 2 buffers x 16 ds_read_b64, each batch = 2 items; consume waits at
// lgkmcnt(16) with a full 16-read batch still in flight (LDS FIFO returns
// in order). Candidate set bit-identical to R1/R2. 128 VGPR budget at 16
// waves/CU; explicit buffers use ~100. LDS: 128KB table + 16KB temp.
extern __shared__ char dyn_lds[];

__launch_bounds__(1024)
__global__ void scan4r_kernel(const float* __restrict__ lut,
                              const uint4* __restrict__ poffs,
                              unsigned* __restrict__ cand_d,
                              unsigned short* __restrict__ cand_n) {
  char* repb = dyn_lds;                               // 131072 B table
  short* temps = (short*)(dyn_lds + 131072);          // 2048 x 4 i16 (16 KB)
  unsigned long long* tempq = (unsigned long long*)(dyn_lds + 131072);
  const int tid = threadIdx.x;
  const int g = blockIdx.x;

  // ---- quantize: 32 tasks (row rr = t&3, seg = t>>2); wave w does t=w, w+16
  {
    const int w = tid >> 6, lane = tid & 63;
#pragma unroll
    for (int t0 = 0; t0 < 2; t0++) {
      const int t = w + t0 * 16;
      const int rr = t & 3, seg = t >> 2;
      const int row = (g << 2) + rr;
      const int e0 = seg * 256 + lane * 4;
      const float4 v4 = *(const float4*)&lut[row * 2048 + e0];
      float s4 = v4.x + v4.y + v4.z + v4.w;
#pragma unroll
      for (int off = 32; off > 0; off >>= 1) s4 += __shfl_xor(s4, off);
      const float mean = s4 * (1.0f / 256.0f);
      const float vals[4] = {v4.x, v4.y, v4.z, v4.w};
#pragma unroll
      for (int k = 0; k < 4; k++) {
        float f = (vals[k] - mean) * 64.0f;
        f = fmaxf(fminf(f, 32000.0f), -32000.0f);
        temps[(e0 + k) * 4 + rr] = (short)(int)rintf(f);
      }
    }
  }
  __syncthreads();

  // ---- replicate: entries 2*tid, 2*tid+1 -> 8 replicas via b128 writes.
  {
    const int lane = tid & 63;
    const unsigned long long q0 = tempq[tid * 2];
    const unsigned long long q1 = tempq[tid * 2 + 1];
    const uint4 wv = make_uint4((unsigned)q0, (unsigned)(q0 >> 32),
                                (unsigned)q1, (unsigned)(q1 >> 32));
    uint4* repv = (uint4*)dyn_lds;
    const int base = tid * 8;
#pragma unroll
    for (int k = 0; k < 8; k++) {
      const int r = (k + lane) & 7;
      repv[base + r] = wv;
    }
  }
  __syncthreads();

  // ---- scan: 64 items/lane; 2-item batches, 2 batches (32 reads) in flight
  const int r = tid & 7;
  const char* base0 = repb + (r << 4);            // segments 0..3 via imm offs
  const char* base1 = repb + 65536 + (r << 4);    // segments 4..7
  unsigned k0[4], k1[4];
#pragma unroll
  for (int j = 0; j < 4; j++) { k0[j] = 0xFFFFFFFFu; k1[j] = 0xFFFFFFFFu; }

  uint2 A[16], B[16];

#define ISSUE8(BUF, O, cw)                                        \
  {                                                               \
    BUF[(O) + 0] = *(const uint2*)(base0 + ((cw).x & 0xFFFFu));   \
    BUF[(O) + 1] = *(const uint2*)(base0 + ((cw).x >> 16) + 16384); \
    BUF[(O) + 2] = *(const uint2*)(base0 + ((cw).y & 0xFFFFu) + 32768); \
    BUF[(O) + 3] = *(const uint2*)(base0 + ((cw).y >> 16) + 49152); \
    BUF[(O) + 4] = *(const uint2*)(base1 + ((cw).z & 0xFFFFu));   \
    BUF[(O) + 5] = *(const uint2*)(base1 + ((cw).z >> 16) + 16384); \
    BUF[(O) + 6] = *(const uint2*)(base1 + ((cw).w & 0xFFFFu) + 32768); \
    BUF[(O) + 7] = *(const uint2*)(base1 + ((cw).w >> 16) + 49152); \
  }

#define CONSUME8(BUF, O, it)                                      \
  {                                                               \
    int s0, s1, s2, s3;                                           \
    {                                                             \
      const unsigned lo = BUF[(O)].x, hi = BUF[(O)].y;            \
      s0 = (int)(short)lo; s1 = ((int)lo) >> 16;                  \
      s2 = (int)(short)hi; s3 = ((int)hi) >> 16;                  \
    }                                                             \
    _Pragma("unroll")                                             \
    for (int j = 1; j < 8; j++) {                                 \
      const unsigned lo = BUF[(O) + j].x, hi = BUF[(O) + j].y;    \
      s0 += (int)(short)lo; s1 += ((int)lo) >> 16;                \
      s2 += (int)(short)hi; s3 += ((int)hi) >> 16;                \
    }                                                             \
    const int ss[4] = {s0, s1, s2, s3};                           \
    _Pragma("unroll")                                             \
    for (int j = 0; j < 4; j++) {                                 \
      const unsigned key = ((unsigned)(ss[j] + 0x40000) << 6) | (unsigned)(it); \
      const unsigned mx = (k0[j] > key) ? k0[j] : key;            \
      k0[j] = (k0[j] < key) ? k0[j] : key;                        \
      k1[j] = (k1[j] < mx) ? k1[j] : mx;                          \
    }                                                             \
  }

  // prologue: batch A = items 0,1 issued; codes for items 2,3 loaded
  {
    const uint4 c0 = poffs[tid];
    const uint4 c1 = poffs[tid + 1024];
    ISSUE8(A, 0, c0)
    ISSUE8(A, 8, c1)
  }
  uint4 cB0 = poffs[tid + 2048];
  uint4 cB1 = poffs[tid + 3072];

  for (int it = 0; it < 64; it += 4) {
    // issue batch B (items it+2, it+3); 32 reads now in flight
    ISSUE8(B, 0, cB0)
    ISSUE8(B, 8, cB1)
    // prefetch codes for items it+4, it+5 (&63 wrap: tail values dead)
    const uint4 nA0 = poffs[tid + (((it + 4) & 63) << 10)];
    const uint4 nA1 = poffs[tid + (((it + 5) & 63) << 10)];
    // consume batch A (items it, it+1): waits lgkmcnt(16), B still queued
    CONSUME8(A, 0, it)
    CONSUME8(A, 8, it + 1)
    // refill batch A (items it+4, it+5)
    ISSUE8(A, 0, nA0)
    ISSUE8(A, 8, nA1)
    // prefetch codes for items it+6, it+7
    cB0 = poffs[tid + (((it + 6) & 63) << 10)];
    cB1 = poffs[tid + (((it + 7) & 63) << 10)];
    // consume batch B (items it+2, it+3)
    CONSUME8(B, 0, it + 2)
    CONSUME8(B, 8, it + 3)
  }
#undef ISSUE8
#undef CONSUME8

#pragma unroll
  for (int j = 0; j < 4; j++) {
    const int row = (g << 2) + j;
    const int d0 = (int)(k0[j] >> 6) - 0x40000;
    const int d1 = (int)(k1[j] >> 6) - 0x40000;
    const int n0 = tid + (int)((k0[j] & 63u) << 10);
    const int n1 = tid + (int)((k1[j] & 63u) << 10);
    const int ba = row * 2048 + tid * 2;
    *(uint2*)&cand_d[ba] = make_uint2((unsigned)(d0 + 0x40000000),
                                      (unsigned)(d1 + 0x40000000));
    *(unsigned*)&cand_n[ba] = (unsigned)n0 | ((unsigned)n1 << 16);
  }
}

// ---------------- Kernel 3b: fallback 64KB scan (verified) ----------------
__launch_bounds__(512)
__global__ void scan16_kernel(const float* __restrict__ lut,
                              const unsigned long long* __restrict__ pcodes,
                              unsigned* __restrict__ cand_d,
                              unsigned short* __restrict__ cand_n) {
  __shared__ short sRep[32768];
  const int tid = threadIdx.x;
  const int b = blockIdx.x;

  const float4 v4 = *(const float4*)&lut[b * 2048 + tid * 4];
  float s4 = v4.x + v4.y + v4.z + v4.w;
#pragma unroll
  for (int off = 32; off > 0; off >>= 1) s4 += __shfl_xor(s4, off);
  const float mean = s4 * (1.0f / 256.0f);

  const float vals[4] = {v4.x, v4.y, v4.z, v4.w};
#pragma unroll
  for (int k2 = 0; k2 < 4; k2++) {
    float f = (vals[k2] - mean) * 64.0f;
    f = fmaxf(fminf(f, 32000.0f), -32000.0f);
    const int iv = (int)rintf(f);
    const unsigned hw = (unsigned)(unsigned short)iv;
    const unsigned wrd = hw | (hw << 16);
    const uint4 wv = make_uint4(wrd, wrd, wrd, wrd);
    const int e = tid * 4 + k2;
    *(uint4*)&((unsigned*)sRep)[e * 8] = wv;
    *(uint4*)&((unsigned*)sRep)[e * 8 + 4] = wv;
  }
  __syncthreads();

  const int r = tid & 15;
  int d0 = 0x7FFFFFFF, d1 = 0x7FFFFFFF, d2 = 0x7FFFFFFF, d3 = 0x7FFFFFFF;
  int i0 = 0, i1 = 0, i2 = 0, i3 = 0;

  unsigned long long c8 = pcodes[tid];
  for (int it = 0; it < 128; it++) {
    const int n = tid + (it << 9);
    unsigned long long nxt = 0ull;
    if (it < 127) nxt = pcodes[n + 512];
    const unsigned lo = (unsigned)c8;
    const unsigned hi = (unsigned)(c8 >> 32);
    int s;
    s  = sRep[(((lo      ) & 255u) << 4) + r        ];
    s += sRep[(((lo >>  8) & 255u) << 4) + r +  4096];
    s += sRep[(((lo >> 16) & 255u) << 4) + r +  8192];
    s += sRep[(((lo >> 24)       ) << 4) + r + 12288];
    s += sRep[(((hi      ) & 255u) << 4) + r + 16384];
    s += sRep[(((hi >>  8) & 255u) << 4) + r + 20480];
    s += sRep[(((hi >> 16) & 255u) << 4) + r + 24576];
    s += sRep[(((hi >> 24)       ) << 4) + r + 28672];
    if (s < d3) {
      if (s < d1) {
        if (s < d0) { d3 = d2; i3 = i2; d2 = d1; i2 = i1; d1 = d0; i1 = i0; d0 = s; i0 = n; }
        else        { d3 = d2; i3 = i2; d2 = d1; i2 = i1; d1 = s; i1 = n; }
      } else {
        if (s < d2) { d3 = d2; i3 = i2; d2 = s; i2 = n; }
        else        { d3 = s; i3 = n; }
      }
    }
    c8 = nxt;
  }

  const int base = b * 2048 + tid * 4;
  const uint4 dv = make_uint4((unsigned)(d0 + 0x40000000), (unsigned)(d1 + 0x40000000),
                              (unsigned)(d2 + 0x40000000), (unsigned)(d3 + 0x40000000));
  *(uint4*)&cand_d[base] = dv;
  const unsigned ni01 = (unsigned)i0 | ((unsigned)i1 << 16);
  const unsigned ni23 = (unsigned)i2 | ((unsigned)i3 << 16);
  *(uint2*)&cand_n[base] = make_uint2(ni01, ni23);
}

// ---------------- Kernel 4: SORT-FREE select + softmax + value gather --------
// Threshold sMin+1024 (was +2048): dropped candidates have weight
// <= exp(-16) = 1.1e-7 relative -- numerically irrelevant vs absmax scale;
// halves the L2-bound value-gather loop and reduces clist-overflow risk.
__launch_bounds__(256)
__global__ void select_kernel(const unsigned* __restrict__ cand_d,
                              const unsigned short* __restrict__ cand_n,
                              const int* __restrict__ value_codes,
                              const float* __restrict__ vcb,
                              const float* __restrict__ bias,
                              float* __restrict__ out) {
  __shared__ unsigned sredw[4];
  __shared__ unsigned long long clist[256];
  __shared__ float sw[256];
  __shared__ int svc[2048];
  __shared__ int scnt;
  __shared__ float sWsum;

  const int tid = threadIdx.x;
  const int b = blockIdx.x;

  const uint4 a0 = *(const uint4*)&cand_d[b * 2048 + tid * 8];
  const uint4 a1 = *(const uint4*)&cand_d[b * 2048 + tid * 8 + 4];
  const uint4 nn = *(const uint4*)&cand_n[b * 2048 + tid * 8];
  unsigned dk[8] = {a0.x, a0.y, a0.z, a0.w, a1.x, a1.y, a1.z, a1.w};
  unsigned ni[8] = {nn.x & 0xFFFFu, nn.x >> 16, nn.y & 0xFFFFu, nn.y >> 16,
                    nn.z & 0xFFFFu, nn.z >> 16, nn.w & 0xFFFFu, nn.w >> 16};

  if (tid == 0) scnt = 0;
  unsigned mn = dk[0];
#pragma unroll
  for (int j = 1; j < 8; j++) mn = (dk[j] < mn) ? dk[j] : mn;
#pragma unroll
  for (int off = 32; off > 0; off >>= 1) {
    const unsigned o = __shfl_xor(mn, off);
    mn = (o < mn) ? o : mn;
  }
  if ((tid & 63) == 0) sredw[tid >> 6] = mn;
  __syncthreads();
  unsigned sMin = sredw[0];
  sMin = (sredw[1] < sMin) ? sredw[1] : sMin;
  sMin = (sredw[2] < sMin) ? sredw[2] : sMin;
  sMin = (sredw[3] < sMin) ? sredw[3] : sMin;
  const unsigned lim = sMin + 1024u;

  const int lane = tid & 63;
  const unsigned long long lm = (1ull << lane) - 1ull;
#pragma unroll
  for (int j = 0; j < 8; j++) {
    const bool pred = dk[j] <= lim;
    const unsigned long long mask = __ballot(pred);
    int base = 0;
    if (lane == 0 && mask) base = atomicAdd(&scnt, __popcll(mask));
    base = __shfl(base, 0);
    if (pred) {
      const int pos = base + __popcll(mask & lm);
      if (pos < 256) clist[pos] = ((unsigned long long)dk[j] << 32) | ni[j];
    }
  }
  __syncthreads();
  const int cnt = min(scnt, 256);

  if (tid < cnt) {
    const int gap = (int)((unsigned)(clist[tid] >> 32)) - (int)sMin;
    sw[tid] = __expf((float)gap * -0.015625f);
  }
  for (int i = tid; i < (cnt << 3); i += 256)
    svc[i] = value_codes[((int)(clist[i >> 3] & 0xFFFFFFFFu)) * 8 + (i & 7)];
  __syncthreads();

  if (tid < 64) {
    float s = 0.f;
    for (int j = tid; j < cnt; j += 64) s += sw[j];
#pragma unroll
    for (int off = 32; off > 0; off >>= 1) s += __shfl_xor(s, off);
    if (tid == 0) sWsum = s;
  }
  __syncthreads();
  const float inv = 1.0f / sWsum;

  const int c0 = tid << 3;
  const int mv = c0 >> 8;
  const int off = c0 & 255;
  float4 acc0 = make_float4(0.f, 0.f, 0.f, 0.f);
  float4 acc1 = make_float4(0.f, 0.f, 0.f, 0.f);
  const float* vbase = vcb + mv * 65536 + off;
  for (int k = 0; k < cnt; k++) {
    const float w = sw[k];
    const float* vp = vbase + svc[(k << 3) + mv] * 256;
    const float4 v0 = *(const float4*)vp;
    const float4 v1 = *(const float4*)(vp + 4);
    acc0.x = fmaf(w, v0.x, acc0.x); acc0.y = fmaf(w, v0.y, acc0.y);
    acc0.z = fmaf(w, v0.z, acc0.z); acc0.w = fmaf(w, v0.w, acc0.w);
    acc1.x = fmaf(w, v1.x, acc1.x); acc1.y = fmaf(w, v1.y, acc1.y);
    acc1.z = fmaf(w, v1.z, acc1.z); acc1.w = fmaf(w, v1.w, acc1.w);
  }
  const float4 b0 = *(const float4*)&bias[c0];
  const float4 b1 = *(const float4*)&bias[c0 + 4];
  *(float4*)&out[b * 2048 + c0] =
      make_float4(fmaf(acc0.x, inv, b0.x), fmaf(acc0.y, inv, b0.y),
                  fmaf(acc0.z, inv, b0.z), fmaf(acc0.w, inv, b0.w));
  *(float4*)&out[b * 2048 + c0 + 4] =
      make_float4(fmaf(acc1.x, inv, b1.x), fmaf(acc1.y, inv, b1.y),
                  fmaf(acc1.z, inv, b1.z), fmaf(acc1.w, inv, b1.w));
}

// ---------------- launch ----------------
extern "C" void kernel_launch(void* const* d_in, const int* in_sizes, int n_in,
                              void* d_out, int out_size, void* d_ws, size_t ws_size,
                              hipStream_t stream) {
  const float* x    = (const float*)d_in[0];
  const float* W    = (const float*)d_in[1];
  const float* kcb  = (const float*)d_in[2];
  const float* vcb  = (const float*)d_in[3];
  const float* bias = (const float*)d_in[4];
  const int* key_codes   = (const int*)d_in[5];
  const int* value_codes = (const int*)d_in[6];
  float* out = (float*)d_out;

  // ws (25.5 MB): qpart 16MB | lut 8MB | poffs 1MB | pcodes 0.5MB.
  // cand buffers alias qpart (dead after lut; written by scan afterwards).
  float* qpart = (float*)d_ws;
  float* lut   = qpart + 4194304;
  uint4* poffs = (uint4*)(lut + 2097152);
  unsigned long long* pcodes = (unsigned long long*)(poffs + 65536);
  unsigned* cand_d = (unsigned*)d_ws;
  unsigned short* cand_n = (unsigned short*)(cand_d + 2097152);

  hipLaunchKernelGGL(gemm_q_kernel, dim3(8, 8, 4), dim3(256), 0, stream,
                     x, W, qpart);
  hipLaunchKernelGGL(lut_kernel, dim3(4, 16, 9), dim3(256), 0, stream,
                     qpart, kcb, key_codes, lut, pcodes, poffs);

  const hipError_t attr_rc = hipFuncSetAttribute(
      (const void*)scan4r_kernel, hipFuncAttributeMaxDynamicSharedMemorySize, 147456);
  if (attr_rc == hipSuccess) {
    hipLaunchKernelGGL(scan4r_kernel, dim3(256), dim3(1024), 147456, stream,
                       lut, poffs, cand_d, cand_n);
  } else {
    hipLaunchKernelGGL(scan16_kernel, dim3(1024), dim3(512), 0, stream,
                       lut, pcodes, cand_d, cand_n);
  }

  hipLaunchKernelGGL(select_kernel, dim3(1024), dim3(256), 0, stream,
                     cand_d, cand_n, value_codes, vcb, bias, out);
}

// Round 5
// 171.222 us; speedup vs baseline: 1.1125x; 1.1125x over previous
//
#include <hip/hip_runtime.h>

#define N_ITEMS 65536

// ---------------- Kernel 1: qpart[z] = x @ W (K-chunk 256 per z) ----------------
__launch_bounds__(256)
__global__ void gemm_q_kernel(const float* __restrict__ A,
                              const float* __restrict__ W,
                              float* __restrict__ qpart) {
  __shared__ float As[16][132];
  __shared__ float Bs[16][132];
  const int tid = threadIdx.x;
  const int tx = tid & 15, ty = tid >> 4;
  const int rb = blockIdx.y * 128, cb = blockIdx.x * 128;
  const int kz = blockIdx.z * 256;
  const int ar = tid >> 2, ac = (tid & 3) << 2;
  const int bk = tid >> 5, bc = (tid & 31) << 2;

  float4 va0 = *(const float4*)&A[(rb + ar) * 1024 + kz + ac];
  float4 va1 = *(const float4*)&A[(rb + ar + 64) * 1024 + kz + ac];
  float4 vb0 = *(const float4*)&W[(kz + bk) * 1024 + cb + bc];
  float4 vb1 = *(const float4*)&W[(kz + bk + 8) * 1024 + cb + bc];

  float acc[8][8] = {};
  for (int k0 = 0; k0 < 256; k0 += 16) {
    As[ac + 0][ar] = va0.x; As[ac + 1][ar] = va0.y;
    As[ac + 2][ar] = va0.z; As[ac + 3][ar] = va0.w;
    As[ac + 0][ar + 64] = va1.x; As[ac + 1][ar + 64] = va1.y;
    As[ac + 2][ar + 64] = va1.z; As[ac + 3][ar + 64] = va1.w;
    *(float4*)&Bs[bk][bc] = vb0;
    *(float4*)&Bs[bk + 8][bc] = vb1;
    __syncthreads();
    if (k0 + 16 < 256) {
      va0 = *(const float4*)&A[(rb + ar) * 1024 + kz + k0 + 16 + ac];
      va1 = *(const float4*)&A[(rb + ar + 64) * 1024 + kz + k0 + 16 + ac];
      vb0 = *(const float4*)&W[(kz + k0 + 16 + bk) * 1024 + cb + bc];
      vb1 = *(const float4*)&W[(kz + k0 + 16 + bk + 8) * 1024 + cb + bc];
    }
#pragma unroll
    for (int kk = 0; kk < 16; kk++) {
      const float4 a0 = *(const float4*)&As[kk][ty << 2];
      const float4 a1 = *(const float4*)&As[kk][64 + (ty << 2)];
      const float4 b0 = *(const float4*)&Bs[kk][tx << 2];
      const float4 b1 = *(const float4*)&Bs[kk][64 + (tx << 2)];
      const float ar8[8] = {a0.x, a0.y, a0.z, a0.w, a1.x, a1.y, a1.z, a1.w};
      const float br8[8] = {b0.x, b0.y, b0.z, b0.w, b1.x, b1.y, b1.z, b1.w};
#pragma unroll
      for (int r = 0; r < 8; r++)
#pragma unroll
        for (int c = 0; c < 8; c++)
          acc[r][c] = fmaf(ar8[r], br8[c], acc[r][c]);
    }
    __syncthreads();
  }
  float* outp = qpart + blockIdx.z * 1048576;
#pragma unroll
  for (int rh = 0; rh < 2; rh++)
#pragma unroll
    for (int r = 0; r < 4; r++) {
      const int row = rb + rh * 64 + (ty << 2) + r;
      const int ri = rh * 4 + r;
      *(float4*)&outp[row * 1024 + cb + (tx << 2)] =
          make_float4(acc[ri][0], acc[ri][1], acc[ri][2], acc[ri][3]);
      *(float4*)&outp[row * 1024 + cb + 64 + (tx << 2)] =
          make_float4(acc[ri][4], acc[ri][5], acc[ri][6], acc[ri][7]);
    }
}

// ---------------- Kernel 2: lut + in-register qsq/csq + code packing ----------
// pack plane (i8 4-row table): h = segment-local byte offset = c*64
// (entry stride = 16 replica dwords = 64 B; max 16320, fits u16).
__launch_bounds__(256)
__global__ void lut_kernel(const float* __restrict__ qpart,
                           const float* __restrict__ kcb,
                           const int* __restrict__ key_codes,
                           float* __restrict__ lut,
                           unsigned long long* __restrict__ pcodes,
                           uint4* __restrict__ poffs) {
  if (blockIdx.z == 8) {
    const int g0 = (((int)blockIdx.y * 4 + (int)blockIdx.x) * 256 + (int)threadIdx.x) * 4;
#pragma unroll
    for (int t = 0; t < 4; t++) {
      const int gid = g0 + t;
      unsigned long long p = 0ull;
      unsigned h[8];
#pragma unroll
      for (int j = 0; j < 8; j++) {
        const unsigned c = (unsigned)key_codes[gid * 8 + j] & 255u;
        p |= (unsigned long long)c << (8 * j);
        h[j] = c << 6;
      }
      pcodes[gid] = p;
      poffs[gid] = make_uint4(h[0] | (h[1] << 16), h[2] | (h[3] << 16),
                              h[4] | (h[5] << 16), h[6] | (h[7] << 16));
    }
    return;
  }

  __shared__ float As[32][68];
  __shared__ float Bs[32][68];
  const int tid = threadIdx.x;
  const int tx = tid & 15, ty = tid >> 4;
  const int m = blockIdx.z;
  const int rb = blockIdx.y * 64;
  const int cb0 = blockIdx.x * 64;
  float acc[4][4] = {};
  float qa[4] = {}, cs[4] = {};
  for (int k0 = 0; k0 < 128; k0 += 32) {
#pragma unroll
    for (int l = 0; l < 2; l++) {
      const int e = tid + l * 256;
      const int row = e >> 3, c4 = (e & 7) << 2;
      const int qidx = (rb + row) * 1024 + m * 128 + k0 + c4;
      const float4 p0 = *(const float4*)&qpart[qidx];
      const float4 p1 = *(const float4*)&qpart[qidx + 1048576];
      const float4 p2 = *(const float4*)&qpart[qidx + 2097152];
      const float4 p3 = *(const float4*)&qpart[qidx + 3145728];
      const float4 va = make_float4(p0.x + p1.x + p2.x + p3.x,
                                    p0.y + p1.y + p2.y + p3.y,
                                    p0.z + p1.z + p2.z + p3.z,
                                    p0.w + p1.w + p2.w + p3.w);
      As[c4 + 0][row] = va.x; As[c4 + 1][row] = va.y;
      As[c4 + 2][row] = va.z; As[c4 + 3][row] = va.w;
      const float4 vb = *(const float4*)&kcb[(m * 256 + cb0 + row) * 128 + k0 + c4];
      Bs[c4 + 0][row] = vb.x; Bs[c4 + 1][row] = vb.y;
      Bs[c4 + 2][row] = vb.z; Bs[c4 + 3][row] = vb.w;
    }
    __syncthreads();
#pragma unroll
    for (int kk = 0; kk < 32; kk++) {
      const float4 a = *(const float4*)&As[kk][ty << 2];
      const float4 b = *(const float4*)&Bs[kk][tx << 2];
      const float ar[4] = {a.x, a.y, a.z, a.w};
      const float br[4] = {b.x, b.y, b.z, b.w};
#pragma unroll
      for (int r = 0; r < 4; r++)
#pragma unroll
        for (int c = 0; c < 4; c++)
          acc[r][c] = fmaf(ar[r], br[c], acc[r][c]);
#pragma unroll
      for (int r = 0; r < 4; r++) qa[r] = fmaf(ar[r], ar[r], qa[r]);
#pragma unroll
      for (int c = 0; c < 4; c++) cs[c] = fmaf(br[c], br[c], cs[c]);
    }
    __syncthreads();
  }
#pragma unroll
  for (int r = 0; r < 4; r++) {
    const int row = rb + (ty << 2) + r;
    const int col = cb0 + (tx << 2);
    float4 v;
    v.x = qa[r] + cs[0] - 2.0f * acc[r][0];
    v.y = qa[r] + cs[1] - 2.0f * acc[r][1];
    v.z = qa[r] + cs[2] - 2.0f * acc[r][2];
    v.w = qa[r] + cs[3] - 2.0f * acc[r][3];
    *(float4*)&lut[row * 2048 + m * 256 + col] = v;
  }
}

// ---------------- Kernel 3a: 4-ROW i8 ADC scan, 16 replicas, SWAR sums ------
// Table: entry = dword of 4 rows x u8 (scale 1, bias +128; clamp +-127;
// per-sum error bounded +-4 lut units -- select re-scores exactly, so scan
// only needs ordering within an 8-unit window). 16 replica dwords per entry
// -> 128 KB, lane r=tid&15 reads dword e*16+r: bank = r + 16*(c&1) -> max 4
// lanes over 2 banks/replica (2-way is free, m136) -> near-zero conflicts
// vs R2's 33.6k cyc/CU. ds_read_b32 x8/item @5.8cyc = 47.5k cyc LDS;
// SWAR dual-u16 accumulation (max 8*255=2040, no overflow) cuts unpack.
// Keeps R2's proven 2-deep ping-pong. LDS: 128KB table + 8KB temp.
extern __shared__ char dyn_lds[];

__launch_bounds__(1024)
__global__ void scan1b_kernel(const float* __restrict__ lut,
                              const uint4* __restrict__ poffs,
                              unsigned* __restrict__ cand_d,
                              unsigned short* __restrict__ cand_n) {
  char* repb = dyn_lds;                               // 131072 B table
  unsigned char* temps = (unsigned char*)(dyn_lds + 131072);  // 2048 B*4 (8 KB)
  unsigned* tempw = (unsigned*)(dyn_lds + 131072);
  const int tid = threadIdx.x;
  const int g = blockIdx.x;

  // ---- quantize: 32 tasks (row rr = t&3, seg = t>>2); wave w does t=w, w+16
  {
    const int w = tid >> 6, lane = tid & 63;
#pragma unroll
    for (int t0 = 0; t0 < 2; t0++) {
      const int t = w + t0 * 16;
      const int rr = t & 3, seg = t >> 2;
      const int row = (g << 2) + rr;
      const int e0 = seg * 256 + lane * 4;
      const float4 v4 = *(const float4*)&lut[row * 2048 + e0];
      float s4 = v4.x + v4.y + v4.z + v4.w;
#pragma unroll
      for (int off = 32; off > 0; off >>= 1) s4 += __shfl_xor(s4, off);
      const float mean = s4 * (1.0f / 256.0f);
      const float vals[4] = {v4.x, v4.y, v4.z, v4.w};
#pragma unroll
      for (int k = 0; k < 4; k++) {
        int iv = (int)rintf(vals[k] - mean);
        iv = max(-127, min(127, iv));
        temps[(e0 + k) * 4 + rr] = (unsigned char)(iv + 128);
      }
    }
  }
  __syncthreads();

  // ---- replicate: entry e -> 16 consecutive dwords (e*16+r), all = packed
  // rows. Thread handles entries 2*tid (banks 0-15) and 2*tid+1 (banks
  // 16-31): the paired b128 writes hit disjoint bank halves; lane stagger
  // spreads the 4 bank-groups within each half.
  {
    const int lane = tid & 63;
    const unsigned v0 = tempw[tid * 2];
    const unsigned v1 = tempw[tid * 2 + 1];
    const uint4 q0 = make_uint4(v0, v0, v0, v0);
    const uint4 q1 = make_uint4(v1, v1, v1, v1);
    uint4* repv = (uint4*)dyn_lds;
#pragma unroll
    for (int k = 0; k < 4; k++) {
      const int kk = (k + lane) & 3;
      repv[tid * 8 + kk] = q0;
      repv[tid * 8 + 4 + kk] = q1;
    }
  }
  __syncthreads();

  // ---- scan: 64 items/lane, ping-pong-buffered 8 dword lookups/item ----
  const int r = tid & 15;
  const char* base0 = repb + (r << 2);            // segments 0..3 via imm offs
  const char* base1 = repb + 65536 + (r << 2);    // segments 4..7
  unsigned k0[4], k1[4];
#pragma unroll
  for (int j = 0; j < 4; j++) { k0[j] = 0xFFFFFFFFu; k1[j] = 0xFFFFFFFFu; }

  unsigned A[8], B[8];

  auto issue = [&](unsigned (&BUF)[8], const uint4 cw) {
    BUF[0] = *(const unsigned*)(base0 + (cw.x & 0xFFFFu));
    BUF[1] = *(const unsigned*)(base0 + (cw.x >> 16) + 16384);
    BUF[2] = *(const unsigned*)(base0 + (cw.y & 0xFFFFu) + 32768);
    BUF[3] = *(const unsigned*)(base0 + (cw.y >> 16) + 49152);
    BUF[4] = *(const unsigned*)(base1 + (cw.z & 0xFFFFu));
    BUF[5] = *(const unsigned*)(base1 + (cw.z >> 16) + 16384);
    BUF[6] = *(const unsigned*)(base1 + (cw.w & 0xFFFFu) + 32768);
    BUF[7] = *(const unsigned*)(base1 + (cw.w >> 16) + 49152);
  };

  auto consume = [&](const unsigned (&BUF)[8], const int it) {
    const unsigned M = 0x00FF00FFu;
    unsigned accA = BUF[0] & M;
    unsigned accB = (BUF[0] >> 8) & M;
#pragma unroll
    for (int j = 1; j < 8; j++) {
      accA += BUF[j] & M;
      accB += (BUF[j] >> 8) & M;
    }
    const int ss[4] = {(int)(accA & 0xFFFFu), (int)(accB & 0xFFFFu),
                       (int)(accA >> 16), (int)(accB >> 16)};
#pragma unroll
    for (int j = 0; j < 4; j++) {
      const unsigned key = ((unsigned)ss[j] << 6) | (unsigned)it;
      const unsigned mx = (k0[j] > key) ? k0[j] : key;
      k0[j] = (k0[j] < key) ? k0[j] : key;
      k1[j] = (k1[j] < mx) ? k1[j] : mx;
    }
  };

  {
    const uint4 cA = poffs[tid];
    issue(A, cA);
  }
  uint4 cNxt = poffs[tid + 1024];   // codes for item 1

  for (int it = 0; it < 64; it += 2) {
    const uint4 c2 = poffs[tid + (((it + 2) & 63) << 10)];
    const uint4 c3 = poffs[tid + (((it + 3) & 63) << 10)];
    issue(B, cNxt);          // item it+1 reads in flight
    consume(A, it);          // waits only A
    issue(A, c2);            // item it+2 reads in flight (dead at it=62)
    consume(B, it + 1);      // waits only B
    cNxt = c3;
  }

#pragma unroll
  for (int j = 0; j < 4; j++) {
    const int row = (g << 2) + j;
    const unsigned d0 = k0[j] >> 6;   // biased u16 sum, unsigned-comparable
    const unsigned d1 = k1[j] >> 6;
    const int n0 = tid + (int)((k0[j] & 63u) << 10);
    const int n1 = tid + (int)((k1[j] & 63u) << 10);
    const int ba = row * 2048 + tid * 2;
    *(uint2*)&cand_d[ba] = make_uint2(d0, d1);
    *(unsigned*)&cand_n[ba] = (unsigned)n0 | ((unsigned)n1 << 16);
  }
}

// ---------------- Kernel 3b: fallback 64KB scan (verified) ----------------
__launch_bounds__(512)
__global__ void scan16_kernel(const float* __restrict__ lut,
                              const unsigned long long* __restrict__ pcodes,
                              unsigned* __restrict__ cand_d,
                              unsigned short* __restrict__ cand_n) {
  __shared__ short sRep[32768];
  const int tid = threadIdx.x;
  const int b = blockIdx.x;

  const float4 v4 = *(const float4*)&lut[b * 2048 + tid * 4];
  float s4 = v4.x + v4.y + v4.z + v4.w;
#pragma unroll
  for (int off = 32; off > 0; off >>= 1) s4 += __shfl_xor(s4, off);
  const float mean = s4 * (1.0f / 256.0f);

  const float vals[4] = {v4.x, v4.y, v4.z, v4.w};
#pragma unroll
  for (int k2 = 0; k2 < 4; k2++) {
    float f = (vals[k2] - mean) * 64.0f;
    f = fmaxf(fminf(f, 32000.0f), -32000.0f);
    const int iv = (int)rintf(f);
    const unsigned hw = (unsigned)(unsigned short)iv;
    const unsigned wrd = hw | (hw << 16);
    const uint4 wv = make_uint4(wrd, wrd, wrd, wrd);
    const int e = tid * 4 + k2;
    *(uint4*)&((unsigned*)sRep)[e * 8] = wv;
    *(uint4*)&((unsigned*)sRep)[e * 8 + 4] = wv;
  }
  __syncthreads();

  const int r = tid & 15;
  int d0 = 0x7FFFFFFF, d1 = 0x7FFFFFFF, d2 = 0x7FFFFFFF, d3 = 0x7FFFFFFF;
  int i0 = 0, i1 = 0, i2 = 0, i3 = 0;

  unsigned long long c8 = pcodes[tid];
  for (int it = 0; it < 128; it++) {
    const int n = tid + (it << 9);
    unsigned long long nxt = 0ull;
    if (it < 127) nxt = pcodes[n + 512];
    const unsigned lo = (unsigned)c8;
    const unsigned hi = (unsigned)(c8 >> 32);
    int s;
    s  = sRep[(((lo      ) & 255u) << 4) + r        ];
    s += sRep[(((lo >>  8) & 255u) << 4) + r +  4096];
    s += sRep[(((lo >> 16) & 255u) << 4) + r +  8192];
    s += sRep[(((lo >> 24)       ) << 4) + r + 12288];
    s += sRep[(((hi      ) & 255u) << 4) + r + 16384];
    s += sRep[(((hi >>  8) & 255u) << 4) + r + 20480];
    s += sRep[(((hi >> 16) & 255u) << 4) + r + 24576];
    s += sRep[(((hi >> 24)       ) << 4) + r + 28672];
    if (s < d3) {
      if (s < d1) {
        if (s < d0) { d3 = d2; i3 = i2; d2 = d1; i2 = i1; d1 = d0; i1 = i0; d0 = s; i0 = n; }
        else        { d3 = d2; i3 = i2; d2 = d1; i2 = i1; d1 = s; i1 = n; }
      } else {
        if (s < d2) { d3 = d2; i3 = i2; d2 = s; i2 = n; }
        else        { d3 = s; i3 = n; }
      }
    }
    c8 = nxt;
  }

  const int base = b * 2048 + tid * 4;
  const uint4 dv = make_uint4((unsigned)(d0 + 0x40000000), (unsigned)(d1 + 0x40000000),
                              (unsigned)(d2 + 0x40000000), (unsigned)(d3 + 0x40000000));
  *(uint4*)&cand_d[base] = dv;
  const unsigned ni01 = (unsigned)i0 | ((unsigned)i1 << 16);
  const unsigned ni23 = (unsigned)i2 | ((unsigned)i3 << 16);
  *(uint2*)&cand_n[base] = make_uint2(ni01, ni23);
}

// ---------------- Kernel 4: select + EXACT fp32 re-score + value gather -----
// Candidate set chosen by quantized threshold (lim_add covers scan quant
// error: i8 path +-8 bounded -> 32; i16 fallback -> 2048); weights computed
// from exact float lut gathers (8 per candidate, L2/L3-resident) -- removes
// the 1/64 weight quantization entirely.
__launch_bounds__(256)
__global__ void select_kernel(const unsigned* __restrict__ cand_d,
                              const unsigned short* __restrict__ cand_n,
                              const int* __restrict__ value_codes,
                              const float* __restrict__ vcb,
                              const float* __restrict__ bias,
                              const unsigned long long* __restrict__ pcodes,
                              const float* __restrict__ lutf,
                              const unsigned lim_add,
                              float* __restrict__ out) {
  __shared__ unsigned sredw[4];
  __shared__ float sredf[4];
  __shared__ unsigned long long clist[256];
  __shared__ float sw[256];
  __shared__ int svc[2048];
  __shared__ int scnt;
  __shared__ float sWsum;

  const int tid = threadIdx.x;
  const int b = blockIdx.x;

  const uint4 a0 = *(const uint4*)&cand_d[b * 2048 + tid * 8];
  const uint4 a1 = *(const uint4*)&cand_d[b * 2048 + tid * 8 + 4];
  const uint4 nn = *(const uint4*)&cand_n[b * 2048 + tid * 8];
  unsigned dk[8] = {a0.x, a0.y, a0.z, a0.w, a1.x, a1.y, a1.z, a1.w};
  unsigned ni[8] = {nn.x & 0xFFFFu, nn.x >> 16, nn.y & 0xFFFFu, nn.y >> 16,
                    nn.z & 0xFFFFu, nn.z >> 16, nn.w & 0xFFFFu, nn.w >> 16};

  if (tid == 0) scnt = 0;
  unsigned mn = dk[0];
#pragma unroll
  for (int j = 1; j < 8; j++) mn = (dk[j] < mn) ? dk[j] : mn;
#pragma unroll
  for (int off = 32; off > 0; off >>= 1) {
    const unsigned o = __shfl_xor(mn, off);
    mn = (o < mn) ? o : mn;
  }
  if ((tid & 63) == 0) sredw[tid >> 6] = mn;
  __syncthreads();
  unsigned sMin = sredw[0];
  sMin = (sredw[1] < sMin) ? sredw[1] : sMin;
  sMin = (sredw[2] < sMin) ? sredw[2] : sMin;
  sMin = (sredw[3] < sMin) ? sredw[3] : sMin;
  const unsigned lim = sMin + lim_add;

  const int lane = tid & 63;
  const unsigned long long lm = (1ull << lane) - 1ull;
#pragma unroll
  for (int j = 0; j < 8; j++) {
    const bool pred = dk[j] <= lim;
    const unsigned long long mask = __ballot(pred);
    int base = 0;
    if (lane == 0 && mask) base = atomicAdd(&scnt, __popcll(mask));
    base = __shfl(base, 0);
    if (pred) {
      const int pos = base + __popcll(mask & lm);
      if (pos < 256) clist[pos] = ((unsigned long long)dk[j] << 32) | ni[j];
    }
  }
  __syncthreads();
  const int cnt = min(scnt, 256);

  // exact re-score of candidates (8 fp32 lut gathers each)
  float dex = 1e30f;
  if (tid < cnt) {
    const int n = (int)(clist[tid] & 0xFFFFFFFFu);
    const unsigned long long c8 = pcodes[n];
    const float* lrow = lutf + b * 2048;
    const unsigned lo = (unsigned)c8, hi = (unsigned)(c8 >> 32);
    dex  = lrow[        (lo       & 255u)];
    dex += lrow[ 256 + ((lo >>  8) & 255u)];
    dex += lrow[ 512 + ((lo >> 16) & 255u)];
    dex += lrow[ 768 + ((lo >> 24)       )];
    dex += lrow[1024 + ( hi        & 255u)];
    dex += lrow[1280 + ((hi >>  8) & 255u)];
    dex += lrow[1536 + ((hi >> 16) & 255u)];
    dex += lrow[1792 + ((hi >> 24)       )];
  }
  for (int i = tid; i < (cnt << 3); i += 256)
    svc[i] = value_codes[((int)(clist[i >> 3] & 0xFFFFFFFFu)) * 8 + (i & 7)];
  float mnf = dex;
#pragma unroll
  for (int off = 32; off > 0; off >>= 1) mnf = fminf(mnf, __shfl_xor(mnf, off));
  if ((tid & 63) == 0) sredf[tid >> 6] = mnf;
  __syncthreads();
  const float dminx = fminf(fminf(sredf[0], sredf[1]), fminf(sredf[2], sredf[3]));
  if (tid < cnt) sw[tid] = __expf(dminx - dex);
  __syncthreads();

  if (tid < 64) {
    float s = 0.f;
    for (int j = tid; j < cnt; j += 64) s += sw[j];
#pragma unroll
    for (int off = 32; off > 0; off >>= 1) s += __shfl_xor(s, off);
    if (tid == 0) sWsum = s;
  }
  __syncthreads();
  const float inv = 1.0f / sWsum;

  const int c0 = tid << 3;
  const int mv = c0 >> 8;
  const int off = c0 & 255;
  float4 acc0 = make_float4(0.f, 0.f, 0.f, 0.f);
  float4 acc1 = make_float4(0.f, 0.f, 0.f, 0.f);
  const float* vbase = vcb + mv * 65536 + off;
  for (int k = 0; k < cnt; k++) {
    const float w = sw[k];
    const float* vp = vbase + svc[(k << 3) + mv] * 256;
    const float4 v0 = *(const float4*)vp;
    const float4 v1 = *(const float4*)(vp + 4);
    acc0.x = fmaf(w, v0.x, acc0.x); acc0.y = fmaf(w, v0.y, acc0.y);
    acc0.z = fmaf(w, v0.z, acc0.z); acc0.w = fmaf(w, v0.w, acc0.w);
    acc1.x = fmaf(w, v1.x, acc1.x); acc1.y = fmaf(w, v1.y, acc1.y);
    acc1.z = fmaf(w, v1.z, acc1.z); acc1.w = fmaf(w, v1.w, acc1.w);
  }
  const float4 b0 = *(const float4*)&bias[c0];
  const float4 b1 = *(const float4*)&bias[c0 + 4];
  *(float4*)&out[b * 2048 + c0] =
      make_float4(fmaf(acc0.x, inv, b0.x), fmaf(acc0.y, inv, b0.y),
                  fmaf(acc0.z, inv, b0.z), fmaf(acc0.w, inv, b0.w));
  *(float4*)&out[b * 2048 + c0 + 4] =
      make_float4(fmaf(acc1.x, inv, b1.x), fmaf(acc1.y, inv, b1.y),
                  fmaf(acc1.z, inv, b1.z), fmaf(acc1.w, inv, b1.w));
}

// ---------------- launch ----------------
extern "C" void kernel_launch(void* const* d_in, const int* in_sizes, int n_in,
                              void* d_out, int out_size, void* d_ws, size_t ws_size,
                              hipStream_t stream) {
  const float* x    = (const float*)d_in[0];
  const float* W    = (const float*)d_in[1];
  const float* kcb  = (const float*)d_in[2];
  const float* vcb  = (const float*)d_in[3];
  const float* bias = (const float*)d_in[4];
  const int* key_codes   = (const int*)d_in[5];
  const int* value_codes = (const int*)d_in[6];
  float* out = (float*)d_out;

  // ws (25.5 MB): qpart 16MB | lut 8MB | poffs 1MB | pcodes 0.5MB.
  // cand buffers alias qpart (dead after lut; written by scan afterwards).
  // lut stays live through select (exact re-scoring).
  float* qpart = (float*)d_ws;
  float* lut   = qpart + 4194304;
  uint4* poffs = (uint4*)(lut + 2097152);
  unsigned long long* pcodes = (unsigned long long*)(poffs + 65536);
  unsigned* cand_d = (unsigned*)d_ws;
  unsigned short* cand_n = (unsigned short*)(cand_d + 2097152);

  hipLaunchKernelGGL(gemm_q_kernel, dim3(8, 8, 4), dim3(256), 0, stream,
                     x, W, qpart);
  hipLaunchKernelGGL(lut_kernel, dim3(4, 16, 9), dim3(256), 0, stream,
                     qpart, kcb, key_codes, lut, pcodes, poffs);

  const hipError_t attr_rc = hipFuncSetAttribute(
      (const void*)scan1b_kernel, hipFuncAttributeMaxDynamicSharedMemorySize, 139264);
  unsigned lim_add;
  if (attr_rc == hipSuccess) {
    hipLaunchKernelGGL(scan1b_kernel, dim3(256), dim3(1024), 139264, stream,
                       lut, poffs, cand_d, cand_n);
    lim_add = 32u;    // i8 scale-1 units: covers exact gap<=16 + bounded error 8
  } else {
    hipLaunchKernelGGL(scan16_kernel, dim3(1024), dim3(512), 0, stream,
                       lut, pcodes, cand_d, cand_n);
    lim_add = 2048u;  // i16 scale-64 units: gap<=32
  }

  hipLaunchKernelGGL(select_kernel, dim3(1024), dim3(256), 0, stream,
                     cand_d, cand_n, value_codes, vcb, bias, pcodes, lut,
                     lim_add, out);
}

// Round 6
// 171.199 us; speedup vs baseline: 1.1126x; 1.0001x over previous
//
#include <hip/hip_runtime.h>

#define N_ITEMS 65536

// ---------------- Kernel 1: qpart[z] = x @ W (K-chunk 128 per z) ------------
// R5: z-split 4->8 (grid 512 = 2 blocks/CU = 2 waves/SIMD) so barrier/load
// stalls of one block hide under the other's FMA stream (was 1 wave/SIMD).
__launch_bounds__(256)
__global__ void gemm_q_kernel(const float* __restrict__ A,
                              const float* __restrict__ W,
                              float* __restrict__ qpart) {
  __shared__ float As[16][132];
  __shared__ float Bs[16][132];
  const int tid = threadIdx.x;
  const int tx = tid & 15, ty = tid >> 4;
  const int rb = blockIdx.y * 128, cb = blockIdx.x * 128;
  const int kz = blockIdx.z * 128;
  const int ar = tid >> 2, ac = (tid & 3) << 2;
  const int bk = tid >> 5, bc = (tid & 31) << 2;

  float4 va0 = *(const float4*)&A[(rb + ar) * 1024 + kz + ac];
  float4 va1 = *(const float4*)&A[(rb + ar + 64) * 1024 + kz + ac];
  float4 vb0 = *(const float4*)&W[(kz + bk) * 1024 + cb + bc];
  float4 vb1 = *(const float4*)&W[(kz + bk + 8) * 1024 + cb + bc];

  float acc[8][8] = {};
  for (int k0 = 0; k0 < 128; k0 += 16) {
    As[ac + 0][ar] = va0.x; As[ac + 1][ar] = va0.y;
    As[ac + 2][ar] = va0.z; As[ac + 3][ar] = va0.w;
    As[ac + 0][ar + 64] = va1.x; As[ac + 1][ar + 64] = va1.y;
    As[ac + 2][ar + 64] = va1.z; As[ac + 3][ar + 64] = va1.w;
    *(float4*)&Bs[bk][bc] = vb0;
    *(float4*)&Bs[bk + 8][bc] = vb1;
    __syncthreads();
    if (k0 + 16 < 128) {
      va0 = *(const float4*)&A[(rb + ar) * 1024 + kz + k0 + 16 + ac];
      va1 = *(const float4*)&A[(rb + ar + 64) * 1024 + kz + k0 + 16 + ac];
      vb0 = *(const float4*)&W[(kz + k0 + 16 + bk) * 1024 + cb + bc];
      vb1 = *(const float4*)&W[(kz + k0 + 16 + bk + 8) * 1024 + cb + bc];
    }
#pragma unroll
    for (int kk = 0; kk < 16; kk++) {
      const float4 a0 = *(const float4*)&As[kk][ty << 2];
      const float4 a1 = *(const float4*)&As[kk][64 + (ty << 2)];
      const float4 b0 = *(const float4*)&Bs[kk][tx << 2];
      const float4 b1 = *(const float4*)&Bs[kk][64 + (tx << 2)];
      const float ar8[8] = {a0.x, a0.y, a0.z, a0.w, a1.x, a1.y, a1.z, a1.w};
      const float br8[8] = {b0.x, b0.y, b0.z, b0.w, b1.x, b1.y, b1.z, b1.w};
#pragma unroll
      for (int r = 0; r < 8; r++)
#pragma unroll
        for (int c = 0; c < 8; c++)
          acc[r][c] = fmaf(ar8[r], br8[c], acc[r][c]);
    }
    __syncthreads();
  }
  float* outp = qpart + blockIdx.z * 1048576;
#pragma unroll
  for (int rh = 0; rh < 2; rh++)
#pragma unroll
    for (int r = 0; r < 4; r++) {
      const int row = rb + rh * 64 + (ty << 2) + r;
      const int ri = rh * 4 + r;
      *(float4*)&outp[row * 1024 + cb + (tx << 2)] =
          make_float4(acc[ri][0], acc[ri][1], acc[ri][2], acc[ri][3]);
      *(float4*)&outp[row * 1024 + cb + 64 + (tx << 2)] =
          make_float4(acc[ri][4], acc[ri][5], acc[ri][6], acc[ri][7]);
    }
}

// ---------------- Kernel 1b: q = sum_z qpart[z] (pure BW, ~36 MB) -----------
__launch_bounds__(256)
__global__ void qsum_kernel(const float4* __restrict__ qp,
                            float4* __restrict__ q) {
  const int i = blockIdx.x * 256 + threadIdx.x;   // 0..131071
  float4 s0 = qp[i];
  float4 s1 = qp[i + 131072];
#pragma unroll
  for (int z = 1; z < 8; z++) {
    const float4 a = qp[z * 262144 + i];
    const float4 b = qp[z * 262144 + i + 131072];
    s0.x += a.x; s0.y += a.y; s0.z += a.z; s0.w += a.w;
    s1.x += b.x; s1.y += b.y; s1.z += b.z; s1.w += b.w;
  }
  q[i] = s0;
  q[i + 131072] = s1;
}

// ---------------- Kernel 2: lut + in-register qsq/csq + code packing ----------
// pack plane (i8 4-row table): h = segment-local byte offset = c*64
// (entry stride = 16 replica dwords = 64 B; max 16320, fits u16).
__launch_bounds__(256)
__global__ void lut_kernel(const float* __restrict__ q,
                           const float* __restrict__ kcb,
                           const int* __restrict__ key_codes,
                           float* __restrict__ lut,
                           unsigned long long* __restrict__ pcodes,
                           uint4* __restrict__ poffs) {
  if (blockIdx.z == 8) {
    const int g0 = (((int)blockIdx.y * 4 + (int)blockIdx.x) * 256 + (int)threadIdx.x) * 4;
#pragma unroll
    for (int t = 0; t < 4; t++) {
      const int gid = g0 + t;
      unsigned long long p = 0ull;
      unsigned h[8];
#pragma unroll
      for (int j = 0; j < 8; j++) {
        const unsigned c = (unsigned)key_codes[gid * 8 + j] & 255u;
        p |= (unsigned long long)c << (8 * j);
        h[j] = c << 6;
      }
      pcodes[gid] = p;
      poffs[gid] = make_uint4(h[0] | (h[1] << 16), h[2] | (h[3] << 16),
                              h[4] | (h[5] << 16), h[6] | (h[7] << 16));
    }
    return;
  }

  __shared__ float As[32][68];
  __shared__ float Bs[32][68];
  const int tid = threadIdx.x;
  const int tx = tid & 15, ty = tid >> 4;
  const int m = blockIdx.z;
  const int rb = blockIdx.y * 64;
  const int cb0 = blockIdx.x * 64;
  float acc[4][4] = {};
  float qa[4] = {}, cs[4] = {};
  for (int k0 = 0; k0 < 128; k0 += 32) {
#pragma unroll
    for (int l = 0; l < 2; l++) {
      const int e = tid + l * 256;
      const int row = e >> 3, c4 = (e & 7) << 2;
      const float4 va = *(const float4*)&q[(rb + row) * 1024 + m * 128 + k0 + c4];
      As[c4 + 0][row] = va.x; As[c4 + 1][row] = va.y;
      As[c4 + 2][row] = va.z; As[c4 + 3][row] = va.w;
      const float4 vb = *(const float4*)&kcb[(m * 256 + cb0 + row) * 128 + k0 + c4];
      Bs[c4 + 0][row] = vb.x; Bs[c4 + 1][row] = vb.y;
      Bs[c4 + 2][row] = vb.z; Bs[c4 + 3][row] = vb.w;
    }
    __syncthreads();
#pragma unroll
    for (int kk = 0; kk < 32; kk++) {
      const float4 a = *(const float4*)&As[kk][ty << 2];
      const float4 b = *(const float4*)&Bs[kk][tx << 2];
      const float ar[4] = {a.x, a.y, a.z, a.w};
      const float br[4] = {b.x, b.y, b.z, b.w};
#pragma unroll
      for (int r = 0; r < 4; r++)
#pragma unroll
        for (int c = 0; c < 4; c++)
          acc[r][c] = fmaf(ar[r], br[c], acc[r][c]);
#pragma unroll
      for (int r = 0; r < 4; r++) qa[r] = fmaf(ar[r], ar[r], qa[r]);
#pragma unroll
      for (int c = 0; c < 4; c++) cs[c] = fmaf(br[c], br[c], cs[c]);
    }
    __syncthreads();
  }
#pragma unroll
  for (int r = 0; r < 4; r++) {
    const int row = rb + (ty << 2) + r;
    const int col = cb0 + (tx << 2);
    float4 v;
    v.x = qa[r] + cs[0] - 2.0f * acc[r][0];
    v.y = qa[r] + cs[1] - 2.0f * acc[r][1];
    v.z = qa[r] + cs[2] - 2.0f * acc[r][2];
    v.w = qa[r] + cs[3] - 2.0f * acc[r][3];
    *(float4*)&lut[row * 2048 + m * 256 + col] = v;
  }
}

// ---------------- Kernel 3a: 4-ROW i8 ADC scan, 16 replicas, SWAR sums ------
// (unchanged from R5: 35us-class, near-zero bank conflicts)
extern __shared__ char dyn_lds[];

__launch_bounds__(1024)
__global__ void scan1b_kernel(const float* __restrict__ lut,
                              const uint4* __restrict__ poffs,
                              unsigned* __restrict__ cand_d,
                              unsigned short* __restrict__ cand_n) {
  char* repb = dyn_lds;                               // 131072 B table
  unsigned char* temps = (unsigned char*)(dyn_lds + 131072);  // 8 KB
  unsigned* tempw = (unsigned*)(dyn_lds + 131072);
  const int tid = threadIdx.x;
  const int g = blockIdx.x;

  // ---- quantize: 32 tasks (row rr = t&3, seg = t>>2); wave w does t=w, w+16
  {
    const int w = tid >> 6, lane = tid & 63;
#pragma unroll
    for (int t0 = 0; t0 < 2; t0++) {
      const int t = w + t0 * 16;
      const int rr = t & 3, seg = t >> 2;
      const int row = (g << 2) + rr;
      const int e0 = seg * 256 + lane * 4;
      const float4 v4 = *(const float4*)&lut[row * 2048 + e0];
      float s4 = v4.x + v4.y + v4.z + v4.w;
#pragma unroll
      for (int off = 32; off > 0; off >>= 1) s4 += __shfl_xor(s4, off);
      const float mean = s4 * (1.0f / 256.0f);
      const float vals[4] = {v4.x, v4.y, v4.z, v4.w};
#pragma unroll
      for (int k = 0; k < 4; k++) {
        int iv = (int)rintf(vals[k] - mean);
        iv = max(-127, min(127, iv));
        temps[(e0 + k) * 4 + rr] = (unsigned char)(iv + 128);
      }
    }
  }
  __syncthreads();

  // ---- replicate: entry e -> 16 consecutive dwords (e*16+r)
  {
    const int lane = tid & 63;
    const unsigned v0 = tempw[tid * 2];
    const unsigned v1 = tempw[tid * 2 + 1];
    const uint4 q0 = make_uint4(v0, v0, v0, v0);
    const uint4 q1 = make_uint4(v1, v1, v1, v1);
    uint4* repv = (uint4*)dyn_lds;
#pragma unroll
    for (int k = 0; k < 4; k++) {
      const int kk = (k + lane) & 3;
      repv[tid * 8 + kk] = q0;
      repv[tid * 8 + 4 + kk] = q1;
    }
  }
  __syncthreads();

  // ---- scan: 64 items/lane, ping-pong-buffered 8 dword lookups/item ----
  const int r = tid & 15;
  const char* base0 = repb + (r << 2);            // segments 0..3 via imm offs
  const char* base1 = repb + 65536 + (r << 2);    // segments 4..7
  unsigned k0[4], k1[4];
#pragma unroll
  for (int j = 0; j < 4; j++) { k0[j] = 0xFFFFFFFFu; k1[j] = 0xFFFFFFFFu; }

  unsigned A[8], B[8];

  auto issue = [&](unsigned (&BUF)[8], const uint4 cw) {
    BUF[0] = *(const unsigned*)(base0 + (cw.x & 0xFFFFu));
    BUF[1] = *(const unsigned*)(base0 + (cw.x >> 16) + 16384);
    BUF[2] = *(const unsigned*)(base0 + (cw.y & 0xFFFFu) + 32768);
    BUF[3] = *(const unsigned*)(base0 + (cw.y >> 16) + 49152);
    BUF[4] = *(const unsigned*)(base1 + (cw.z & 0xFFFFu));
    BUF[5] = *(const unsigned*)(base1 + (cw.z >> 16) + 16384);
    BUF[6] = *(const unsigned*)(base1 + (cw.w & 0xFFFFu) + 32768);
    BUF[7] = *(const unsigned*)(base1 + (cw.w >> 16) + 49152);
  };

  auto consume = [&](const unsigned (&BUF)[8], const int it) {
    const unsigned M = 0x00FF00FFu;
    unsigned accA = BUF[0] & M;
    unsigned accB = (BUF[0] >> 8) & M;
#pragma unroll
    for (int j = 1; j < 8; j++) {
      accA += BUF[j] & M;
      accB += (BUF[j] >> 8) & M;
    }
    const int ss[4] = {(int)(accA & 0xFFFFu), (int)(accB & 0xFFFFu),
                       (int)(accA >> 16), (int)(accB >> 16)};
#pragma unroll
    for (int j = 0; j < 4; j++) {
      const unsigned key = ((unsigned)ss[j] << 6) | (unsigned)it;
      const unsigned mx = (k0[j] > key) ? k0[j] : key;
      k0[j] = (k0[j] < key) ? k0[j] : key;
      k1[j] = (k1[j] < mx) ? k1[j] : mx;
    }
  };

  {
    const uint4 cA = poffs[tid];
    issue(A, cA);
  }
  uint4 cNxt = poffs[tid + 1024];   // codes for item 1

  for (int it = 0; it < 64; it += 2) {
    const uint4 c2 = poffs[tid + (((it + 2) & 63) << 10)];
    const uint4 c3 = poffs[tid + (((it + 3) & 63) << 10)];
    issue(B, cNxt);          // item it+1 reads in flight
    consume(A, it);          // waits only A
    issue(A, c2);            // item it+2 reads in flight (dead at it=62)
    consume(B, it + 1);      // waits only B
    cNxt = c3;
  }

#pragma unroll
  for (int j = 0; j < 4; j++) {
    const int row = (g << 2) + j;
    const unsigned d0 = k0[j] >> 6;   // biased u16 sum, unsigned-comparable
    const unsigned d1 = k1[j] >> 6;
    const int n0 = tid + (int)((k0[j] & 63u) << 10);
    const int n1 = tid + (int)((k1[j] & 63u) << 10);
    const int ba = row * 2048 + tid * 2;
    *(uint2*)&cand_d[ba] = make_uint2(d0, d1);
    *(unsigned*)&cand_n[ba] = (unsigned)n0 | ((unsigned)n1 << 16);
  }
}

// ---------------- Kernel 3b: fallback 64KB scan (verified) ----------------
__launch_bounds__(512)
__global__ void scan16_kernel(const float* __restrict__ lut,
                              const unsigned long long* __restrict__ pcodes,
                              unsigned* __restrict__ cand_d,
                              unsigned short* __restrict__ cand_n) {
  __shared__ short sRep[32768];
  const int tid = threadIdx.x;
  const int b = blockIdx.x;

  const float4 v4 = *(const float4*)&lut[b * 2048 + tid * 4];
  float s4 = v4.x + v4.y + v4.z + v4.w;
#pragma unroll
  for (int off = 32; off > 0; off >>= 1) s4 += __shfl_xor(s4, off);
  const float mean = s4 * (1.0f / 256.0f);

  const float vals[4] = {v4.x, v4.y, v4.z, v4.w};
#pragma unroll
  for (int k2 = 0; k2 < 4; k2++) {
    float f = (vals[k2] - mean) * 64.0f;
    f = fmaxf(fminf(f, 32000.0f), -32000.0f);
    const int iv = (int)rintf(f);
    const unsigned hw = (unsigned)(unsigned short)iv;
    const unsigned wrd = hw | (hw << 16);
    const uint4 wv = make_uint4(wrd, wrd, wrd, wrd);
    const int e = tid * 4 + k2;
    *(uint4*)&((unsigned*)sRep)[e * 8] = wv;
    *(uint4*)&((unsigned*)sRep)[e * 8 + 4] = wv;
  }
  __syncthreads();

  const int r = tid & 15;
  int d0 = 0x7FFFFFFF, d1 = 0x7FFFFFFF, d2 = 0x7FFFFFFF, d3 = 0x7FFFFFFF;
  int i0 = 0, i1 = 0, i2 = 0, i3 = 0;

  unsigned long long c8 = pcodes[tid];
  for (int it = 0; it < 128; it++) {
    const int n = tid + (it << 9);
    unsigned long long nxt = 0ull;
    if (it < 127) nxt = pcodes[n + 512];
    const unsigned lo = (unsigned)c8;
    const unsigned hi = (unsigned)(c8 >> 32);
    int s;
    s  = sRep[(((lo      ) & 255u) << 4) + r        ];
    s += sRep[(((lo >>  8) & 255u) << 4) + r +  4096];
    s += sRep[(((lo >> 16) & 255u) << 4) + r +  8192];
    s += sRep[(((lo >> 24)       ) << 4) + r + 12288];
    s += sRep[(((hi      ) & 255u) << 4) + r + 16384];
    s += sRep[(((hi >>  8) & 255u) << 4) + r + 20480];
    s += sRep[(((hi >> 16) & 255u) << 4) + r + 24576];
    s += sRep[(((hi >> 24)       ) << 4) + r + 28672];
    if (s < d3) {
      if (s < d1) {
        if (s < d0) { d3 = d2; i3 = i2; d2 = d1; i2 = i1; d1 = d0; i1 = i0; d0 = s; i0 = n; }
        else        { d3 = d2; i3 = i2; d2 = d1; i2 = i1; d1 = s; i1 = n; }
      } else {
        if (s < d2) { d3 = d2; i3 = i2; d2 = s; i2 = n; }
        else        { d3 = s; i3 = n; }
      }
    }
    c8 = nxt;
  }

  const int base = b * 2048 + tid * 4;
  const uint4 dv = make_uint4((unsigned)(d0 + 0x40000000), (unsigned)(d1 + 0x40000000),
                              (unsigned)(d2 + 0x40000000), (unsigned)(d3 + 0x40000000));
  *(uint4*)&cand_d[base] = dv;
  const unsigned ni01 = (unsigned)i0 | ((unsigned)i1 << 16);
  const unsigned ni23 = (unsigned)i2 | ((unsigned)i3 << 16);
  *(uint2*)&cand_n[base] = make_uint2(ni01, ni23);
}

// ---------------- Kernel 4: select + EXACT fp32 re-score + value gather -----
// lim_add 20 (i8 path): quant gap error bounded +-8, so every exact-gap<=12
// candidate kept; dropped ones have weight < 6e-6 -- invisible at absmax
// 1.6e-2 scale. Gather loop unrolled x2 for MLP on L2-resident vcb.
__launch_bounds__(256)
__global__ void select_kernel(const unsigned* __restrict__ cand_d,
                              const unsigned short* __restrict__ cand_n,
                              const int* __restrict__ value_codes,
                              const float* __restrict__ vcb,
                              const float* __restrict__ bias,
                              const unsigned long long* __restrict__ pcodes,
                              const float* __restrict__ lutf,
                              const unsigned lim_add,
                              float* __restrict__ out) {
  __shared__ unsigned sredw[4];
  __shared__ float sredf[4];
  __shared__ unsigned long long clist[256];
  __shared__ float sw[256];
  __shared__ int svc[2048];
  __shared__ int scnt;
  __shared__ float sWsum;

  const int tid = threadIdx.x;
  const int b = blockIdx.x;

  const uint4 a0 = *(const uint4*)&cand_d[b * 2048 + tid * 8];
  const uint4 a1 = *(const uint4*)&cand_d[b * 2048 + tid * 8 + 4];
  const uint4 nn = *(const uint4*)&cand_n[b * 2048 + tid * 8];
  unsigned dk[8] = {a0.x, a0.y, a0.z, a0.w, a1.x, a1.y, a1.z, a1.w};
  unsigned ni[8] = {nn.x & 0xFFFFu, nn.x >> 16, nn.y & 0xFFFFu, nn.y >> 16,
                    nn.z & 0xFFFFu, nn.z >> 16, nn.w & 0xFFFFu, nn.w >> 16};

  if (tid == 0) scnt = 0;
  unsigned mn = dk[0];
#pragma unroll
  for (int j = 1; j < 8; j++) mn = (dk[j] < mn) ? dk[j] : mn;
#pragma unroll
  for (int off = 32; off > 0; off >>= 1) {
    const unsigned o = __shfl_xor(mn, off);
    mn = (o < mn) ? o : mn;
  }
  if ((tid & 63) == 0) sredw[tid >> 6] = mn;
  __syncthreads();
  unsigned sMin = sredw[0];
  sMin = (sredw[1] < sMin) ? sredw[1] : sMin;
  sMin = (sredw[2] < sMin) ? sredw[2] : sMin;
  sMin = (sredw[3] < sMin) ? sredw[3] : sMin;
  const unsigned lim = sMin + lim_add;

  const int lane = tid & 63;
  const unsigned long long lm = (1ull << lane) - 1ull;
#pragma unroll
  for (int j = 0; j < 8; j++) {
    const bool pred = dk[j] <= lim;
    const unsigned long long mask = __ballot(pred);
    int base = 0;
    if (lane == 0 && mask) base = atomicAdd(&scnt, __popcll(mask));
    base = __shfl(base, 0);
    if (pred) {
      const int pos = base + __popcll(mask & lm);
      if (pos < 256) clist[pos] = ((unsigned long long)dk[j] << 32) | ni[j];
    }
  }
  __syncthreads();
  const int cnt = min(scnt, 256);

  // exact re-score of candidates (8 fp32 lut gathers each)
  float dex = 1e30f;
  if (tid < cnt) {
    const int n = (int)(clist[tid] & 0xFFFFFFFFu);
    const unsigned long long c8 = pcodes[n];
    const float* lrow = lutf + b * 2048;
    const unsigned lo = (unsigned)c8, hi = (unsigned)(c8 >> 32);
    dex  = lrow[        (lo       & 255u)];
    dex += lrow[ 256 + ((lo >>  8) & 255u)];
    dex += lrow[ 512 + ((lo >> 16) & 255u)];
    dex += lrow[ 768 + ((lo >> 24)       )];
    dex += lrow[1024 + ( hi        & 255u)];
    dex += lrow[1280 + ((hi >>  8) & 255u)];
    dex += lrow[1536 + ((hi >> 16) & 255u)];
    dex += lrow[1792 + ((hi >> 24)       )];
  }
  for (int i = tid; i < (cnt << 3); i += 256)
    svc[i] = value_codes[((int)(clist[i >> 3] & 0xFFFFFFFFu)) * 8 + (i & 7)];
  float mnf = dex;
#pragma unroll
  for (int off = 32; off > 0; off >>= 1) mnf = fminf(mnf, __shfl_xor(mnf, off));
  if ((tid & 63) == 0) sredf[tid >> 6] = mnf;
  __syncthreads();
  const float dminx = fminf(fminf(sredf[0], sredf[1]), fminf(sredf[2], sredf[3]));
  if (tid < cnt) sw[tid] = __expf(dminx - dex);
  __syncthreads();

  if (tid < 64) {
    float s = 0.f;
    for (int j = tid; j < cnt; j += 64) s += sw[j];
#pragma unroll
    for (int off = 32; off > 0; off >>= 1) s += __shfl_xor(s, off);
    if (tid == 0) sWsum = s;
  }
  __syncthreads();
  const float inv = 1.0f / sWsum;

  const int c0 = tid << 3;
  const int mv = c0 >> 8;
  const int off = c0 & 255;
  float4 acc0 = make_float4(0.f, 0.f, 0.f, 0.f);
  float4 acc1 = make_float4(0.f, 0.f, 0.f, 0.f);
  const float* vbase = vcb + mv * 65536 + off;
  int k = 0;
  for (; k + 1 < cnt; k += 2) {
    const float w0 = sw[k];
    const float w1 = sw[k + 1];
    const float* vp0 = vbase + svc[(k << 3) + mv] * 256;
    const float* vp1 = vbase + svc[((k + 1) << 3) + mv] * 256;
    const float4 p0 = *(const float4*)vp0;
    const float4 p1 = *(const float4*)(vp0 + 4);
    const float4 r0 = *(const float4*)vp1;
    const float4 r1 = *(const float4*)(vp1 + 4);
    acc0.x = fmaf(w0, p0.x, acc0.x); acc0.y = fmaf(w0, p0.y, acc0.y);
    acc0.z = fmaf(w0, p0.z, acc0.z); acc0.w = fmaf(w0, p0.w, acc0.w);
    acc1.x = fmaf(w0, p1.x, acc1.x); acc1.y = fmaf(w0, p1.y, acc1.y);
    acc1.z = fmaf(w0, p1.z, acc1.z); acc1.w = fmaf(w0, p1.w, acc1.w);
    acc0.x = fmaf(w1, r0.x, acc0.x); acc0.y = fmaf(w1, r0.y, acc0.y);
    acc0.z = fmaf(w1, r0.z, acc0.z); acc0.w = fmaf(w1, r0.w, acc0.w);
    acc1.x = fmaf(w1, r1.x, acc1.x); acc1.y = fmaf(w1, r1.y, acc1.y);
    acc1.z = fmaf(w1, r1.z, acc1.z); acc1.w = fmaf(w1, r1.w, acc1.w);
  }
  if (k < cnt) {
    const float w = sw[k];
    const float* vp = vbase + svc[(k << 3) + mv] * 256;
    const float4 v0 = *(const float4*)vp;
    const float4 v1 = *(const float4*)(vp + 4);
    acc0.x = fmaf(w, v0.x, acc0.x); acc0.y = fmaf(w, v0.y, acc0.y);
    acc0.z = fmaf(w, v0.z, acc0.z); acc0.w = fmaf(w, v0.w, acc0.w);
    acc1.x = fmaf(w, v1.x, acc1.x); acc1.y = fmaf(w, v1.y, acc1.y);
    acc1.z = fmaf(w, v1.z, acc1.z); acc1.w = fmaf(w, v1.w, acc1.w);
  }
  const float4 b0 = *(const float4*)&bias[c0];
  const float4 b1 = *(const float4*)&bias[c0 + 4];
  *(float4*)&out[b * 2048 + c0] =
      make_float4(fmaf(acc0.x, inv, b0.x), fmaf(acc0.y, inv, b0.y),
                  fmaf(acc0.z, inv, b0.z), fmaf(acc0.w, inv, b0.w));
  *(float4*)&out[b * 2048 + c0 + 4] =
      make_float4(fmaf(acc1.x, inv, b1.x), fmaf(acc1.y, inv, b1.y),
                  fmaf(acc1.z, inv, b1.z), fmaf(acc1.w, inv, b1.w));
}

// ---------------- launch ----------------
extern "C" void kernel_launch(void* const* d_in, const int* in_sizes, int n_in,
                              void* d_out, int out_size, void* d_ws, size_t ws_size,
                              hipStream_t stream) {
  const float* x    = (const float*)d_in[0];
  const float* W    = (const float*)d_in[1];
  const float* kcb  = (const float*)d_in[2];
  const float* vcb  = (const float*)d_in[3];
  const float* bias = (const float*)d_in[4];
  const int* key_codes   = (const int*)d_in[5];
  const int* value_codes = (const int*)d_in[6];
  float* out = (float*)d_out;

  // ws (~47.5 MB; d_ws is 256 MiB per harness fill): qpart 32MB | q 4MB |
  // lut 8MB | poffs 1MB | pcodes 0.5MB. cand buffers alias qpart (dead after
  // qsum). lut stays live through select (exact re-scoring).
  float* qpart = (float*)d_ws;
  float* q     = qpart + 8388608;
  float* lut   = q + 1048576;
  uint4* poffs = (uint4*)(lut + 2097152);
  unsigned long long* pcodes = (unsigned long long*)(poffs + 65536);
  unsigned* cand_d = (unsigned*)d_ws;
  unsigned short* cand_n = (unsigned short*)(cand_d + 2097152);

  hipLaunchKernelGGL(gemm_q_kernel, dim3(8, 8, 8), dim3(256), 0, stream,
                     x, W, qpart);
  hipLaunchKernelGGL(qsum_kernel, dim3(512), dim3(256), 0, stream,
                     (const float4*)qpart, (float4*)q);
  hipLaunchKernelGGL(lut_kernel, dim3(4, 16, 9), dim3(256), 0, stream,
                     q, kcb, key_codes, lut, pcodes, poffs);

  const hipError_t attr_rc = hipFuncSetAttribute(
      (const void*)scan1b_kernel, hipFuncAttributeMaxDynamicSharedMemorySize, 139264);
  unsigned lim_add;
  if (attr_rc == hipSuccess) {
    hipLaunchKernelGGL(scan1b_kernel, dim3(256), dim3(1024), 139264, stream,
                       lut, poffs, cand_d, cand_n);
    lim_add = 20u;    // exact gap<=12 guaranteed kept (quant error bound 8)
  } else {
    hipLaunchKernelGGL(scan16_kernel, dim3(1024), dim3(512), 0, stream,
                       lut, pcodes, cand_d, cand_n);
    lim_add = 1024u;  // i16 scale-64 units: gap<=16
  }

  hipLaunchKernelGGL(select_kernel, dim3(1024), dim3(256), 0, stream,
                     cand_d, cand_n, value_codes, vcb, bias, pcodes, lut,
                     lim_add, out);
}

// Round 7
// 165.940 us; speedup vs baseline: 1.1479x; 1.0317x over previous
//
#include <hip/hip_runtime.h>

#define N_ITEMS 65536

// ---------------- Kernel 1: qpart[z] = x @ W (K-chunk 128 per z) ------------
__launch_bounds__(256)
__global__ void gemm_q_kernel(const float* __restrict__ A,
                              const float* __restrict__ W,
                              float* __restrict__ qpart) {
  __shared__ float As[16][132];
  __shared__ float Bs[16][132];
  const int tid = threadIdx.x;
  const int tx = tid & 15, ty = tid >> 4;
  const int rb = blockIdx.y * 128, cb = blockIdx.x * 128;
  const int kz = blockIdx.z * 128;
  const int ar = tid >> 2, ac = (tid & 3) << 2;
  const int bk = tid >> 5, bc = (tid & 31) << 2;

  float4 va0 = *(const float4*)&A[(rb + ar) * 1024 + kz + ac];
  float4 va1 = *(const float4*)&A[(rb + ar + 64) * 1024 + kz + ac];
  float4 vb0 = *(const float4*)&W[(kz + bk) * 1024 + cb + bc];
  float4 vb1 = *(const float4*)&W[(kz + bk + 8) * 1024 + cb + bc];

  float acc[8][8] = {};
  for (int k0 = 0; k0 < 128; k0 += 16) {
    As[ac + 0][ar] = va0.x; As[ac + 1][ar] = va0.y;
    As[ac + 2][ar] = va0.z; As[ac + 3][ar] = va0.w;
    As[ac + 0][ar + 64] = va1.x; As[ac + 1][ar + 64] = va1.y;
    As[ac + 2][ar + 64] = va1.z; As[ac + 3][ar + 64] = va1.w;
    *(float4*)&Bs[bk][bc] = vb0;
    *(float4*)&Bs[bk + 8][bc] = vb1;
    __syncthreads();
    if (k0 + 16 < 128) {
      va0 = *(const float4*)&A[(rb + ar) * 1024 + kz + k0 + 16 + ac];
      va1 = *(const float4*)&A[(rb + ar + 64) * 1024 + kz + k0 + 16 + ac];
      vb0 = *(const float4*)&W[(kz + k0 + 16 + bk) * 1024 + cb + bc];
      vb1 = *(const float4*)&W[(kz + k0 + 16 + bk + 8) * 1024 + cb + bc];
    }
#pragma unroll
    for (int kk = 0; kk < 16; kk++) {
      const float4 a0 = *(const float4*)&As[kk][ty << 2];
      const float4 a1 = *(const float4*)&As[kk][64 + (ty << 2)];
      const float4 b0 = *(const float4*)&Bs[kk][tx << 2];
      const float4 b1 = *(const float4*)&Bs[kk][64 + (tx << 2)];
      const float ar8[8] = {a0.x, a0.y, a0.z, a0.w, a1.x, a1.y, a1.z, a1.w};
      const float br8[8] = {b0.x, b0.y, b0.z, b0.w, b1.x, b1.y, b1.z, b1.w};
#pragma unroll
      for (int r = 0; r < 8; r++)
#pragma unroll
        for (int c = 0; c < 8; c++)
          acc[r][c] = fmaf(ar8[r], br8[c], acc[r][c]);
    }
    __syncthreads();
  }
  float* outp = qpart + blockIdx.z * 1048576;
#pragma unroll
  for (int rh = 0; rh < 2; rh++)
#pragma unroll
    for (int r = 0; r < 4; r++) {
      const int row = rb + rh * 64 + (ty << 2) + r;
      const int ri = rh * 4 + r;
      *(float4*)&outp[row * 1024 + cb + (tx << 2)] =
          make_float4(acc[ri][0], acc[ri][1], acc[ri][2], acc[ri][3]);
      *(float4*)&outp[row * 1024 + cb + 64 + (tx << 2)] =
          make_float4(acc[ri][4], acc[ri][5], acc[ri][6], acc[ri][7]);
    }
}

// ---------------- Kernel 1b: q = sum_z qpart[z] (pure BW) -------------------
__launch_bounds__(256)
__global__ void qsum_kernel(const float4* __restrict__ qp,
                            float4* __restrict__ q) {
  const int i = blockIdx.x * 256 + threadIdx.x;   // 0..131071
  float4 s0 = qp[i];
  float4 s1 = qp[i + 131072];
#pragma unroll
  for (int z = 1; z < 8; z++) {
    const float4 a = qp[z * 262144 + i];
    const float4 b = qp[z * 262144 + i + 131072];
    s0.x += a.x; s0.y += a.y; s0.z += a.z; s0.w += a.w;
    s1.x += b.x; s1.y += b.y; s1.z += b.z; s1.w += b.w;
  }
  q[i] = s0;
  q[i + 131072] = s1;
}

// ---------------- Kernel 2: lut + in-register qsq/csq + code packing ----------
__launch_bounds__(256)
__global__ void lut_kernel(const float* __restrict__ q,
                           const float* __restrict__ kcb,
                           const int* __restrict__ key_codes,
                           float* __restrict__ lut,
                           unsigned long long* __restrict__ pcodes,
                           uint4* __restrict__ poffs) {
  if (blockIdx.z == 8) {
    const int g0 = (((int)blockIdx.y * 4 + (int)blockIdx.x) * 256 + (int)threadIdx.x) * 4;
#pragma unroll
    for (int t = 0; t < 4; t++) {
      const int gid = g0 + t;
      unsigned long long p = 0ull;
      unsigned h[8];
#pragma unroll
      for (int j = 0; j < 8; j++) {
        const unsigned c = (unsigned)key_codes[gid * 8 + j] & 255u;
        p |= (unsigned long long)c << (8 * j);
        h[j] = c << 6;
      }
      pcodes[gid] = p;
      poffs[gid] = make_uint4(h[0] | (h[1] << 16), h[2] | (h[3] << 16),
                              h[4] | (h[5] << 16), h[6] | (h[7] << 16));
    }
    return;
  }

  __shared__ float As[32][68];
  __shared__ float Bs[32][68];
  const int tid = threadIdx.x;
  const int tx = tid & 15, ty = tid >> 4;
  const int m = blockIdx.z;
  const int rb = blockIdx.y * 64;
  const int cb0 = blockIdx.x * 64;
  float acc[4][4] = {};
  float qa[4] = {}, cs[4] = {};
  for (int k0 = 0; k0 < 128; k0 += 32) {
#pragma unroll
    for (int l = 0; l < 2; l++) {
      const int e = tid + l * 256;
      const int row = e >> 3, c4 = (e & 7) << 2;
      const float4 va = *(const float4*)&q[(rb + row) * 1024 + m * 128 + k0 + c4];
      As[c4 + 0][row] = va.x; As[c4 + 1][row] = va.y;
      As[c4 + 2][row] = va.z; As[c4 + 3][row] = va.w;
      const float4 vb = *(const float4*)&kcb[(m * 256 + cb0 + row) * 128 + k0 + c4];
      Bs[c4 + 0][row] = vb.x; Bs[c4 + 1][row] = vb.y;
      Bs[c4 + 2][row] = vb.z; Bs[c4 + 3][row] = vb.w;
    }
    __syncthreads();
#pragma unroll
    for (int kk = 0; kk < 32; kk++) {
      const float4 a = *(const float4*)&As[kk][ty << 2];
      const float4 b = *(const float4*)&Bs[kk][tx << 2];
      const float ar[4] = {a.x, a.y, a.z, a.w};
      const float br[4] = {b.x, b.y, b.z, b.w};
#pragma unroll
      for (int r = 0; r < 4; r++)
#pragma unroll
        for (int c = 0; c < 4; c++)
          acc[r][c] = fmaf(ar[r], br[c], acc[r][c]);
#pragma unroll
      for (int r = 0; r < 4; r++) qa[r] = fmaf(ar[r], ar[r], qa[r]);
#pragma unroll
      for (int c = 0; c < 4; c++) cs[c] = fmaf(br[c], br[c], cs[c]);
    }
    __syncthreads();
  }
#pragma unroll
  for (int r = 0; r < 4; r++) {
    const int row = rb + (ty << 2) + r;
    const int col = cb0 + (tx << 2);
    float4 v;
    v.x = qa[r] + cs[0] - 2.0f * acc[r][0];
    v.y = qa[r] + cs[1] - 2.0f * acc[r][1];
    v.z = qa[r] + cs[2] - 2.0f * acc[r][2];
    v.w = qa[r] + cs[3] - 2.0f * acc[r][3];
    *(float4*)&lut[row * 2048 + m * 256 + col] = v;
  }
}

// ---------------- Kernel 3a: FUSED i8 ADC scan + select + gather ------------
// R6 post-mortem: select's cost is mostly fixed overhead (12MB cand round-
// trip, 2048-cand reduce) -- but the scan block already holds all 2048
// candidates/row in registers. Fuse: after the scan loop the 128KB table is
// dead; overlay LDS with {clist, weights, packed value-codes}; min-reduce
// (shfl + 64 atomicMin), ballot-compact, exact fp32 re-score from global
// lut, softmax, value gather, write out. Candidate set + weights identical
// to R6's select (lim_add=20); only summation order differs.
extern __shared__ char dyn_lds[];

__launch_bounds__(1024)
__global__ void scansel_kernel(const float* __restrict__ lutf,
                               const uint4* __restrict__ poffs,
                               const unsigned long long* __restrict__ pcodes,
                               const int* __restrict__ value_codes,
                               const float* __restrict__ vcb,
                               const float* __restrict__ bias,
                               float* __restrict__ out) {
  char* repb = dyn_lds;                               // 131072 B table
  unsigned char* temps = (unsigned char*)(dyn_lds + 131072);  // 8 KB
  unsigned* tempw = (unsigned*)(dyn_lds + 131072);
  const int tid = threadIdx.x;
  const int g = blockIdx.x;

  // ---- quantize: 32 tasks (row rr = t&3, seg = t>>2); wave w does t=w, w+16
  {
    const int w = tid >> 6, lane = tid & 63;
#pragma unroll
    for (int t0 = 0; t0 < 2; t0++) {
      const int t = w + t0 * 16;
      const int rr = t & 3, seg = t >> 2;
      const int row = (g << 2) + rr;
      const int e0 = seg * 256 + lane * 4;
      const float4 v4 = *(const float4*)&lutf[row * 2048 + e0];
      float s4 = v4.x + v4.y + v4.z + v4.w;
#pragma unroll
      for (int off = 32; off > 0; off >>= 1) s4 += __shfl_xor(s4, off);
      const float mean = s4 * (1.0f / 256.0f);
      const float vals[4] = {v4.x, v4.y, v4.z, v4.w};
#pragma unroll
      for (int k = 0; k < 4; k++) {
        int iv = (int)rintf(vals[k] - mean);
        iv = max(-127, min(127, iv));
        temps[(e0 + k) * 4 + rr] = (unsigned char)(iv + 128);
      }
    }
  }
  __syncthreads();

  // ---- replicate: entry e -> 16 consecutive dwords (e*16+r)
  {
    const int lane = tid & 63;
    const unsigned v0 = tempw[tid * 2];
    const unsigned v1 = tempw[tid * 2 + 1];
    const uint4 q0 = make_uint4(v0, v0, v0, v0);
    const uint4 q1 = make_uint4(v1, v1, v1, v1);
    uint4* repv = (uint4*)dyn_lds;
#pragma unroll
    for (int k = 0; k < 4; k++) {
      const int kk = (k + lane) & 3;
      repv[tid * 8 + kk] = q0;
      repv[tid * 8 + 4 + kk] = q1;
    }
  }
  __syncthreads();

  // ---- scan: 64 items/lane, ping-pong-buffered 8 dword lookups/item ----
  const int r = tid & 15;
  const char* base0 = repb + (r << 2);            // segments 0..3 via imm offs
  const char* base1 = repb + 65536 + (r << 2);    // segments 4..7
  unsigned k0[4], k1[4];
#pragma unroll
  for (int j = 0; j < 4; j++) { k0[j] = 0xFFFFFFFFu; k1[j] = 0xFFFFFFFFu; }

  unsigned A[8], B[8];

  auto issue = [&](unsigned (&BUF)[8], const uint4 cw) {
    BUF[0] = *(const unsigned*)(base0 + (cw.x & 0xFFFFu));
    BUF[1] = *(const unsigned*)(base0 + (cw.x >> 16) + 16384);
    BUF[2] = *(const unsigned*)(base0 + (cw.y & 0xFFFFu) + 32768);
    BUF[3] = *(const unsigned*)(base0 + (cw.y >> 16) + 49152);
    BUF[4] = *(const unsigned*)(base1 + (cw.z & 0xFFFFu));
    BUF[5] = *(const unsigned*)(base1 + (cw.z >> 16) + 16384);
    BUF[6] = *(const unsigned*)(base1 + (cw.w & 0xFFFFu) + 32768);
    BUF[7] = *(const unsigned*)(base1 + (cw.w >> 16) + 49152);
  };

  auto consume = [&](const unsigned (&BUF)[8], const int it) {
    const unsigned M = 0x00FF00FFu;
    unsigned accA = BUF[0] & M;
    unsigned accB = (BUF[0] >> 8) & M;
#pragma unroll
    for (int j = 1; j < 8; j++) {
      accA += BUF[j] & M;
      accB += (BUF[j] >> 8) & M;
    }
    const int ss[4] = {(int)(accA & 0xFFFFu), (int)(accB & 0xFFFFu),
                       (int)(accA >> 16), (int)(accB >> 16)};
#pragma unroll
    for (int j = 0; j < 4; j++) {
      const unsigned key = ((unsigned)ss[j] << 6) | (unsigned)it;
      const unsigned mx = (k0[j] > key) ? k0[j] : key;
      k0[j] = (k0[j] < key) ? k0[j] : key;
      k1[j] = (k1[j] < mx) ? k1[j] : mx;
    }
  };

  {
    const uint4 cA = poffs[tid];
    issue(A, cA);
  }
  uint4 cNxt = poffs[tid + 1024];

  for (int it = 0; it < 64; it += 2) {
    const uint4 c2 = poffs[tid + (((it + 2) & 63) << 10)];
    const uint4 c3 = poffs[tid + (((it + 3) & 63) << 10)];
    issue(B, cNxt);
    consume(A, it);
    issue(A, c2);
    consume(B, it + 1);
    cNxt = c3;
  }

  // ================= SELECT PHASE (table is dead; overlay LDS) =============
  __syncthreads();   // all table reads complete before overlay writes

  unsigned* cl  = (unsigned*)dyn_lds;                       // [4][256] (d<<16)|n
  float* wts    = (float*)(dyn_lds + 4096);                 // [4][256]
  unsigned long long* sv8 = (unsigned long long*)(dyn_lds + 8192); // [4][256]
  float* gred   = (float*)(dyn_lds + 16384);                // [4][4] scratch
  unsigned* rmin = (unsigned*)(dyn_lds + 16448);            // [4]
  int* rcnt     = (int*)(dyn_lds + 16464);                  // [4]
  float* rws    = (float*)(dyn_lds + 16480);                // [4] 1/wsum

  if (tid < 4) { rmin[tid] = 0xFFFFFFFFu; rcnt[tid] = 0; }
  __syncthreads();

  // per-row quantized min
#pragma unroll
  for (int j = 0; j < 4; j++) {
    unsigned d = k0[j] >> 6;
#pragma unroll
    for (int off = 32; off > 0; off >>= 1) {
      const unsigned o = __shfl_xor(d, off);
      d = (o < d) ? o : d;
    }
    if ((tid & 63) == 0) atomicMin(&rmin[j], d);
  }
  __syncthreads();

  // ballot-compact candidates within window
  {
    const int lane = tid & 63;
    const unsigned long long lm = (1ull << lane) - 1ull;
#pragma unroll
    for (int j = 0; j < 4; j++) {
      const unsigned lim = rmin[j] + 20u;
#pragma unroll
      for (int c = 0; c < 2; c++) {
        const unsigned key = c ? k1[j] : k0[j];
        const unsigned d = key >> 6;
        const bool pred = d <= lim;
        const unsigned long long m = __ballot(pred);
        int base = 0;
        if (lane == 0 && m) base = atomicAdd(&rcnt[j], __popcll(m));
        base = __shfl(base, 0);
        if (pred) {
          const int pos = base + __popcll(m & lm);
          if (pos < 256)
            cl[j * 256 + pos] = (d << 16) | ((key & 63u) << 10) | (unsigned)tid;
        }
      }
    }
  }
  __syncthreads();

  // exact fp32 re-score (group j = tid>>8 handles row j)
  const int gj = tid >> 8, gt = tid & 255;
  const int cnt_g = min(rcnt[gj], 256);
  float dex = 1e30f;
  if (gt < cnt_g) {
    const unsigned pc = cl[gj * 256 + gt];
    const int n = (int)(pc & 0xFFFFu);
    const unsigned long long c8 = pcodes[n];
    const uint4 vc0 = *(const uint4*)&value_codes[n * 8];
    const uint4 vc1 = *(const uint4*)&value_codes[n * 8 + 4];
    sv8[gj * 256 + gt] =
        (unsigned long long)(vc0.x & 255u)        | ((unsigned long long)(vc0.y & 255u) << 8)  |
        ((unsigned long long)(vc0.z & 255u) << 16) | ((unsigned long long)(vc0.w & 255u) << 24) |
        ((unsigned long long)(vc1.x & 255u) << 32) | ((unsigned long long)(vc1.y & 255u) << 40) |
        ((unsigned long long)(vc1.z & 255u) << 48) | ((unsigned long long)(vc1.w & 255u) << 56);
    const float* lrow = lutf + ((g << 2) + gj) * 2048;
    const unsigned lo = (unsigned)c8, hi = (unsigned)(c8 >> 32);
    dex  = lrow[        (lo       & 255u)];
    dex += lrow[ 256 + ((lo >>  8) & 255u)];
    dex += lrow[ 512 + ((lo >> 16) & 255u)];
    dex += lrow[ 768 + ((lo >> 24)       )];
    dex += lrow[1024 + ( hi        & 255u)];
    dex += lrow[1280 + ((hi >>  8) & 255u)];
    dex += lrow[1536 + ((hi >> 16) & 255u)];
    dex += lrow[1792 + ((hi >> 24)       )];
  }
  // group min of dex (4 waves per group)
  float mnf = dex;
#pragma unroll
  for (int off = 32; off > 0; off >>= 1) mnf = fminf(mnf, __shfl_xor(mnf, off));
  if ((tid & 63) == 0) gred[gj * 4 + ((tid >> 6) & 3)] = mnf;
  __syncthreads();
  const float dminx = fminf(fminf(gred[gj * 4], gred[gj * 4 + 1]),
                            fminf(gred[gj * 4 + 2], gred[gj * 4 + 3]));
  const float w = (gt < cnt_g) ? __expf(dminx - dex) : 0.f;
  wts[gj * 256 + gt] = w;
  // group sum of w
  float sw_ = w;
#pragma unroll
  for (int off = 32; off > 0; off >>= 1) sw_ += __shfl_xor(sw_, off);
  __syncthreads();   // gred min-reads done; safe to overwrite
  if ((tid & 63) == 0) gred[gj * 4 + ((tid >> 6) & 3)] = sw_;
  __syncthreads();
  if (gt == 0)
    rws[gj] = 1.0f / (gred[gj * 4] + gred[gj * 4 + 1] + gred[gj * 4 + 2] + gred[gj * 4 + 3]);
  __syncthreads();

  // value gather + output: rows in pairs (h = tid>>9 selects row of pair)
  const int h = tid >> 9, u = tid & 511;
  const int col = u << 2;
  const int mv = col >> 8;
  const int co = col & 255;
  const float* vb2 = vcb + mv * 65536 + co;
  const float4 bb = *(const float4*)&bias[col];
#pragma unroll
  for (int jr = 0; jr < 2; jr++) {
    const int j = (jr << 1) | h;
    const int row = (g << 2) + j;
    const int cj = min(rcnt[j], 256);
    float4 acc = make_float4(0.f, 0.f, 0.f, 0.f);
    int k = 0;
    for (; k + 1 < cj; k += 2) {
      const float w0 = wts[j * 256 + k];
      const float w1 = wts[j * 256 + k + 1];
      const unsigned c0 = (unsigned)((sv8[j * 256 + k] >> (mv * 8)) & 255ull);
      const unsigned c1 = (unsigned)((sv8[j * 256 + k + 1] >> (mv * 8)) & 255ull);
      const float4 v0 = *(const float4*)(vb2 + c0 * 256);
      const float4 v1 = *(const float4*)(vb2 + c1 * 256);
      acc.x = fmaf(w0, v0.x, acc.x); acc.y = fmaf(w0, v0.y, acc.y);
      acc.z = fmaf(w0, v0.z, acc.z); acc.w = fmaf(w0, v0.w, acc.w);
      acc.x = fmaf(w1, v1.x, acc.x); acc.y = fmaf(w1, v1.y, acc.y);
      acc.z = fmaf(w1, v1.z, acc.z); acc.w = fmaf(w1, v1.w, acc.w);
    }
    if (k < cj) {
      const float w0 = wts[j * 256 + k];
      const unsigned c0 = (unsigned)((sv8[j * 256 + k] >> (mv * 8)) & 255ull);
      const float4 v0 = *(const float4*)(vb2 + c0 * 256);
      acc.x = fmaf(w0, v0.x, acc.x); acc.y = fmaf(w0, v0.y, acc.y);
      acc.z = fmaf(w0, v0.z, acc.z); acc.w = fmaf(w0, v0.w, acc.w);
    }
    const float iv = rws[j];
    *(float4*)&out[row * 2048 + col] =
        make_float4(fmaf(acc.x, iv, bb.x), fmaf(acc.y, iv, bb.y),
                    fmaf(acc.z, iv, bb.z), fmaf(acc.w, iv, bb.w));
  }
}

// ---------------- Kernel 3b: fallback 64KB scan (verified) ----------------
__launch_bounds__(512)
__global__ void scan16_kernel(const float* __restrict__ lut,
                              const unsigned long long* __restrict__ pcodes,
                              unsigned* __restrict__ cand_d,
                              unsigned short* __restrict__ cand_n) {
  __shared__ short sRep[32768];
  const int tid = threadIdx.x;
  const int b = blockIdx.x;

  const float4 v4 = *(const float4*)&lut[b * 2048 + tid * 4];
  float s4 = v4.x + v4.y + v4.z + v4.w;
#pragma unroll
  for (int off = 32; off > 0; off >>= 1) s4 += __shfl_xor(s4, off);
  const float mean = s4 * (1.0f / 256.0f);

  const float vals[4] = {v4.x, v4.y, v4.z, v4.w};
#pragma unroll
  for (int k2 = 0; k2 < 4; k2++) {
    float f = (vals[k2] - mean) * 64.0f;
    f = fmaxf(fminf(f, 32000.0f), -32000.0f);
    const int iv = (int)rintf(f);
    const unsigned hw = (unsigned)(unsigned short)iv;
    const unsigned wrd = hw | (hw << 16);
    const uint4 wv = make_uint4(wrd, wrd, wrd, wrd);
    const int e = tid * 4 + k2;
    *(uint4*)&((unsigned*)sRep)[e * 8] = wv;
    *(uint4*)&((unsigned*)sRep)[e * 8 + 4] = wv;
  }
  __syncthreads();

  const int r = tid & 15;
  int d0 = 0x7FFFFFFF, d1 = 0x7FFFFFFF, d2 = 0x7FFFFFFF, d3 = 0x7FFFFFFF;
  int i0 = 0, i1 = 0, i2 = 0, i3 = 0;

  unsigned long long c8 = pcodes[tid];
  for (int it = 0; it < 128; it++) {
    const int n = tid + (it << 9);
    unsigned long long nxt = 0ull;
    if (it < 127) nxt = pcodes[n + 512];
    const unsigned lo = (unsigned)c8;
    const unsigned hi = (unsigned)(c8 >> 32);
    int s;
    s  = sRep[(((lo      ) & 255u) << 4) + r        ];
    s += sRep[(((lo >>  8) & 255u) << 4) + r +  4096];
    s += sRep[(((lo >> 16) & 255u) << 4) + r +  8192];
    s += sRep[(((lo >> 24)       ) << 4) + r + 12288];
    s += sRep[(((hi      ) & 255u) << 4) + r + 16384];
    s += sRep[(((hi >>  8) & 255u) << 4) + r + 20480];
    s += sRep[(((hi >> 16) & 255u) << 4) + r + 24576];
    s += sRep[(((hi >> 24)       ) << 4) + r + 28672];
    if (s < d3) {
      if (s < d1) {
        if (s < d0) { d3 = d2; i3 = i2; d2 = d1; i2 = i1; d1 = d0; i1 = i0; d0 = s; i0 = n; }
        else        { d3 = d2; i3 = i2; d2 = d1; i2 = i1; d1 = s; i1 = n; }
      } else {
        if (s < d2) { d3 = d2; i3 = i2; d2 = s; i2 = n; }
        else        { d3 = s; i3 = n; }
      }
    }
    c8 = nxt;
  }

  const int base = b * 2048 + tid * 4;
  const uint4 dv = make_uint4((unsigned)(d0 + 0x40000000), (unsigned)(d1 + 0x40000000),
                              (unsigned)(d2 + 0x40000000), (unsigned)(d3 + 0x40000000));
  *(uint4*)&cand_d[base] = dv;
  const unsigned ni01 = (unsigned)i0 | ((unsigned)i1 << 16);
  const unsigned ni23 = (unsigned)i2 | ((unsigned)i3 << 16);
  *(uint2*)&cand_n[base] = make_uint2(ni01, ni23);
}

// ---------------- Kernel 4 (fallback path only): select + re-score ----------
__launch_bounds__(256)
__global__ void select_kernel(const unsigned* __restrict__ cand_d,
                              const unsigned short* __restrict__ cand_n,
                              const int* __restrict__ value_codes,
                              const float* __restrict__ vcb,
                              const float* __restrict__ bias,
                              const unsigned long long* __restrict__ pcodes,
                              const float* __restrict__ lutf,
                              const unsigned lim_add,
                              float* __restrict__ out) {
  __shared__ unsigned sredw[4];
  __shared__ float sredf[4];
  __shared__ unsigned long long clist[256];
  __shared__ float sw[256];
  __shared__ int svc[2048];
  __shared__ int scnt;
  __shared__ float sWsum;

  const int tid = threadIdx.x;
  const int b = blockIdx.x;

  const uint4 a0 = *(const uint4*)&cand_d[b * 2048 + tid * 8];
  const uint4 a1 = *(const uint4*)&cand_d[b * 2048 + tid * 8 + 4];
  const uint4 nn = *(const uint4*)&cand_n[b * 2048 + tid * 8];
  unsigned dk[8] = {a0.x, a0.y, a0.z, a0.w, a1.x, a1.y, a1.z, a1.w};
  unsigned ni[8] = {nn.x & 0xFFFFu, nn.x >> 16, nn.y & 0xFFFFu, nn.y >> 16,
                    nn.z & 0xFFFFu, nn.z >> 16, nn.w & 0xFFFFu, nn.w >> 16};

  if (tid == 0) scnt = 0;
  unsigned mn = dk[0];
#pragma unroll
  for (int j = 1; j < 8; j++) mn = (dk[j] < mn) ? dk[j] : mn;
#pragma unroll
  for (int off = 32; off > 0; off >>= 1) {
    const unsigned o = __shfl_xor(mn, off);
    mn = (o < mn) ? o : mn;
  }
  if ((tid & 63) == 0) sredw[tid >> 6] = mn;
  __syncthreads();
  unsigned sMin = sredw[0];
  sMin = (sredw[1] < sMin) ? sredw[1] : sMin;
  sMin = (sredw[2] < sMin) ? sredw[2] : sMin;
  sMin = (sredw[3] < sMin) ? sredw[3] : sMin;
  const unsigned lim = sMin + lim_add;

  const int lane = tid & 63;
  const unsigned long long lm = (1ull << lane) - 1ull;
#pragma unroll
  for (int j = 0; j < 8; j++) {
    const bool pred = dk[j] <= lim;
    const unsigned long long mask = __ballot(pred);
    int base = 0;
    if (lane == 0 && mask) base = atomicAdd(&scnt, __popcll(mask));
    base = __shfl(base, 0);
    if (pred) {
      const int pos = base + __popcll(mask & lm);
      if (pos < 256) clist[pos] = ((unsigned long long)dk[j] << 32) | ni[j];
    }
  }
  __syncthreads();
  const int cnt = min(scnt, 256);

  float dex = 1e30f;
  if (tid < cnt) {
    const int n = (int)(clist[tid] & 0xFFFFFFFFu);
    const unsigned long long c8 = pcodes[n];
    const float* lrow = lutf + b * 2048;
    const unsigned lo = (unsigned)c8, hi = (unsigned)(c8 >> 32);
    dex  = lrow[        (lo       & 255u)];
    dex += lrow[ 256 + ((lo >>  8) & 255u)];
    dex += lrow[ 512 + ((lo >> 16) & 255u)];
    dex += lrow[ 768 + ((lo >> 24)       )];
    dex += lrow[1024 + ( hi        & 255u)];
    dex += lrow[1280 + ((hi >>  8) & 255u)];
    dex += lrow[1536 + ((hi >> 16) & 255u)];
    dex += lrow[1792 + ((hi >> 24)       )];
  }
  for (int i = tid; i < (cnt << 3); i += 256)
    svc[i] = value_codes[((int)(clist[i >> 3] & 0xFFFFFFFFu)) * 8 + (i & 7)];
  float mnf = dex;
#pragma unroll
  for (int off = 32; off > 0; off >>= 1) mnf = fminf(mnf, __shfl_xor(mnf, off));
  if ((tid & 63) == 0) sredf[tid >> 6] = mnf;
  __syncthreads();
  const float dminx = fminf(fminf(sredf[0], sredf[1]), fminf(sredf[2], sredf[3]));
  if (tid < cnt) sw[tid] = __expf(dminx - dex);
  __syncthreads();

  if (tid < 64) {
    float s = 0.f;
    for (int j = tid; j < cnt; j += 64) s += sw[j];
#pragma unroll
    for (int off = 32; off > 0; off >>= 1) s += __shfl_xor(s, off);
    if (tid == 0) sWsum = s;
  }
  __syncthreads();
  const float inv = 1.0f / sWsum;

  const int c0 = tid << 3;
  const int mv = c0 >> 8;
  const int off = c0 & 255;
  float4 acc0 = make_float4(0.f, 0.f, 0.f, 0.f);
  float4 acc1 = make_float4(0.f, 0.f, 0.f, 0.f);
  const float* vbase = vcb + mv * 65536 + off;
  for (int k = 0; k < cnt; k++) {
    const float w = sw[k];
    const float* vp = vbase + svc[(k << 3) + mv] * 256;
    const float4 v0 = *(const float4*)vp;
    const float4 v1 = *(const float4*)(vp + 4);
    acc0.x = fmaf(w, v0.x, acc0.x); acc0.y = fmaf(w, v0.y, acc0.y);
    acc0.z = fmaf(w, v0.z, acc0.z); acc0.w = fmaf(w, v0.w, acc0.w);
    acc1.x = fmaf(w, v1.x, acc1.x); acc1.y = fmaf(w, v1.y, acc1.y);
    acc1.z = fmaf(w, v1.z, acc1.z); acc1.w = fmaf(w, v1.w, acc1.w);
  }
  const float4 b0 = *(const float4*)&bias[c0];
  const float4 b1 = *(const float4*)&bias[c0 + 4];
  *(float4*)&out[b * 2048 + c0] =
      make_float4(fmaf(acc0.x, inv, b0.x), fmaf(acc0.y, inv, b0.y),
                  fmaf(acc0.z, inv, b0.z), fmaf(acc0.w, inv, b0.w));
  *(float4*)&out[b * 2048 + c0 + 4] =
      make_float4(fmaf(acc1.x, inv, b1.x), fmaf(acc1.y, inv, b1.y),
                  fmaf(acc1.z, inv, b1.z), fmaf(acc1.w, inv, b1.w));
}

// ---------------- launch ----------------
extern "C" void kernel_launch(void* const* d_in, const int* in_sizes, int n_in,
                              void* d_out, int out_size, void* d_ws, size_t ws_size,
                              hipStream_t stream) {
  const float* x    = (const float*)d_in[0];
  const float* W    = (const float*)d_in[1];
  const float* kcb  = (const float*)d_in[2];
  const float* vcb  = (const float*)d_in[3];
  const float* bias = (const float*)d_in[4];
  const int* key_codes   = (const int*)d_in[5];
  const int* value_codes = (const int*)d_in[6];
  float* out = (float*)d_out;

  // ws: qpart 32MB | q 4MB | lut 8MB | poffs 1MB | pcodes 0.5MB.
  // cand buffers (fallback only) alias qpart. lut live through scansel.
  float* qpart = (float*)d_ws;
  float* q     = qpart + 8388608;
  float* lut   = q + 1048576;
  uint4* poffs = (uint4*)(lut + 2097152);
  unsigned long long* pcodes = (unsigned long long*)(poffs + 65536);
  unsigned* cand_d = (unsigned*)d_ws;
  unsigned short* cand_n = (unsigned short*)(cand_d + 2097152);

  hipLaunchKernelGGL(gemm_q_kernel, dim3(8, 8, 8), dim3(256), 0, stream,
                     x, W, qpart);
  hipLaunchKernelGGL(qsum_kernel, dim3(512), dim3(256), 0, stream,
                     (const float4*)qpart, (float4*)q);
  hipLaunchKernelGGL(lut_kernel, dim3(4, 16, 9), dim3(256), 0, stream,
                     q, kcb, key_codes, lut, pcodes, poffs);

  const hipError_t attr_rc = hipFuncSetAttribute(
      (const void*)scansel_kernel, hipFuncAttributeMaxDynamicSharedMemorySize, 139264);
  if (attr_rc == hipSuccess) {
    hipLaunchKernelGGL(scansel_kernel, dim3(256), dim3(1024), 139264, stream,
                       lut, poffs, pcodes, value_codes, vcb, bias, out);
  } else {
    hipLaunchKernelGGL(scan16_kernel, dim3(1024), dim3(512), 0, stream,
                       lut, pcodes, cand_d, cand_n);
    hipLaunchKernelGGL(select_kernel, dim3(1024), dim3(256), 0, stream,
                       cand_d, cand_n, value_codes, vcb, bias, pcodes, lut,
                       1024u, out);
  }
}